// Round 1
// baseline (1423.612 us; speedup 1.0000x reference)
//
#include <hip/hip_runtime.h>
#include <math.h>

#define TT 2048
#define BB 2
#define HH 16
#define DHD 64
#define DMODEL 1024
#define NREL 4095                      // 2*TT-1
#define PSZ (BB * HH * TT * DHD)       // 4194304 floats per projection

// ---------------- bucket (exact-integer replication of reference log math) ---
__device__ __forceinline__ int rel_bucket(int rel) {
    int base = rel > 0 ? 16 : 0;
    int r = rel < 0 ? -rel : rel;
    int lb;
    if (r < 8)       lb = r;
    else if (r < 12) lb = 8;
    else if (r < 16) lb = 9;
    else if (r < 23) lb = 10;
    else if (r < 32) lb = 11;
    else if (r < 46) lb = 12;
    else if (r < 64) lb = 13;
    else if (r < 91) lb = 14;
    else             lb = 15;
    return base + lb;
}

__global__ void bias_table_kernel(const float* __restrict__ rel_bias,
                                  float* __restrict__ btable) {
    int idx = blockIdx.x * blockDim.x + threadIdx.x;
    if (idx >= HH * NREL) return;
    int h = idx / NREL, ri = idx % NREL;
    int bucket = rel_bucket(ri - (TT - 1));
    btable[idx] = rel_bias[bucket * HH + h];   // rel_bias is [32][16]
}

// ---------------- expand bias table to output 1: [H][T][T] -------------------
__global__ void bias_write_kernel(const float* __restrict__ btable,
                                  float* __restrict__ out1) {
    int n4 = HH * TT * TT / 4;                 // 16,777,216
    int stride = gridDim.x * blockDim.x;
    for (int i4 = blockIdx.x * blockDim.x + threadIdx.x; i4 < n4; i4 += stride) {
        int i = i4 * 4;
        int k = i & (TT - 1);
        int q = (i >> 11) & (TT - 1);
        int h = i >> 22;
        const float* bt = btable + h * NREL + (k - q + (TT - 1));
        float4 v = make_float4(bt[0], bt[1], bt[2], bt[3]);
        reinterpret_cast<float4*>(out1)[i4] = v;
    }
}

// ---------------- f32 tiled GEMM: C(MxN) = A(MxK) @ W(KxN) -------------------
// AMODE 0: A row-major [4096][1024].  AMODE 1: A stored as [B][H][T][64].
// CMODE 0: C row-major.               CMODE 1: C stored as [B][H][T][64].
template<int AMODE, int CMODE>
__global__ __launch_bounds__(256) void gemm64(const float* __restrict__ A,
                                              const float* __restrict__ W,
                                              float* __restrict__ C) {
    const int K = DMODEL, N = DMODEL;
    __shared__ float Al[64][20];
    __shared__ float Wl[16][68];
    int bm = blockIdx.x * 64;
    int bn = blockIdx.y * 64;
    int tid = threadIdx.x;
    int ty = tid >> 4, tx = tid & 15;
    int lrow = tid >> 2;            // 0..63  (A-tile row)
    int lk   = (tid & 3) << 2;      // 0,4,8,12
    int wr   = tid >> 4;            // 0..15  (W-tile row)
    int wc   = (tid & 15) << 2;     // 0..60
    float acc[4][4] = {{0.f}};
    for (int k0 = 0; k0 < K; k0 += 16) {
        const float* asrc;
        int gr = bm + lrow;
        int col = k0 + lk;
        if (AMODE == 0) {
            asrc = A + (size_t)gr * K + col;
        } else {
            int b = gr >> 11, t = gr & (TT - 1);
            asrc = A + ((size_t)((b * HH + (col >> 6)) * TT + t) << 6) + (col & 63);
        }
        float4 av = *(const float4*)asrc;
        *(float4*)&Al[lrow][lk] = av;
        float4 wv = *(const float4*)(W + (size_t)(k0 + wr) * N + bn + wc);
        *(float4*)&Wl[wr][wc] = wv;
        __syncthreads();
#pragma unroll
        for (int kk = 0; kk < 16; ++kk) {
            float a0 = Al[ty*4+0][kk], a1 = Al[ty*4+1][kk];
            float a2 = Al[ty*4+2][kk], a3 = Al[ty*4+3][kk];
            float b0 = Wl[kk][tx*4+0], b1 = Wl[kk][tx*4+1];
            float b2 = Wl[kk][tx*4+2], b3 = Wl[kk][tx*4+3];
            acc[0][0] += a0*b0; acc[0][1] += a0*b1; acc[0][2] += a0*b2; acc[0][3] += a0*b3;
            acc[1][0] += a1*b0; acc[1][1] += a1*b1; acc[1][2] += a1*b2; acc[1][3] += a1*b3;
            acc[2][0] += a2*b0; acc[2][1] += a2*b1; acc[2][2] += a2*b2; acc[2][3] += a2*b3;
            acc[3][0] += a3*b0; acc[3][1] += a3*b1; acc[3][2] += a3*b2; acc[3][3] += a3*b3;
        }
        __syncthreads();
    }
#pragma unroll
    for (int i = 0; i < 4; ++i) {
        int r = bm + ty*4 + i;
        float4 cv = make_float4(acc[i][0], acc[i][1], acc[i][2], acc[i][3]);
        if (CMODE == 0) {
            *(float4*)(C + (size_t)r * N + bn + tx*4) = cv;
        } else {
            int n = bn + tx*4;
            int b = r >> 11, t = r & (TT - 1);
            *(float4*)(C + ((size_t)((b * HH + (n >> 6)) * TT + t) << 6) + (n & 63)) = cv;
        }
    }
}

// ---------------- flash attention, f32, Br=16, Bc=64 -------------------------
__global__ __launch_bounds__(256) void attn_kernel(const float* __restrict__ qh,
                                                   const float* __restrict__ kh,
                                                   const float* __restrict__ vh,
                                                   const int*   __restrict__ mask,
                                                   const float* __restrict__ btable,
                                                   float* __restrict__ attnout) {
    __shared__ float Ql[16][68];
    __shared__ float Kl[64][68];
    __shared__ float Vl[64][68];
    __shared__ float Pl[16][68];
    int bid = blockIdx.x;
    int qt = bid & 127;            // T/16 tiles
    int h  = (bid >> 7) & 15;
    int b  = bid >> 11;
    int q0 = qt * 16;
    int tid = threadIdx.x;
    int ty = tid >> 4, tx = tid & 15;

    const float* Qb = qh + ((size_t)((b * HH + h) * TT) << 6);
    const float* Kb = kh + ((size_t)((b * HH + h) * TT) << 6);
    const float* Vb = vh + ((size_t)((b * HH + h) * TT) << 6);

    {   // load Q tile 16x64
        int flat = tid * 4;
        int r = flat >> 6, d = flat & 63;
        float4 v = *(const float4*)(Qb + ((size_t)(q0 + r) << 6) + d);
        *(float4*)&Ql[r][d] = v;
    }

    float m = -INFINITY, l = 0.f;
    float o0 = 0.f, o1 = 0.f, o2 = 0.f, o3 = 0.f;
    const float* btab = btable + h * NREL + (TT - 1) - (q0 + ty);
    const int* mrow = mask + ((size_t)(b * TT + q0 + ty) * TT);

    for (int kt = 0; kt < TT / 64; ++kt) {
        int k0 = kt * 64;
#pragma unroll
        for (int r4 = 0; r4 < 4; ++r4) {       // load K,V tiles 64x64
            int flat = (tid + r4 * 256) * 4;
            int r = flat >> 6, d = flat & 63;
            float4 kv = *(const float4*)(Kb + ((size_t)(k0 + r) << 6) + d);
            *(float4*)&Kl[r][d] = kv;
            float4 vv = *(const float4*)(Vb + ((size_t)(k0 + r) << 6) + d);
            *(float4*)&Vl[r][d] = vv;
        }
        __syncthreads();

        // S for columns j = tx + 16c
        float s0 = 0.f, s1 = 0.f, s2 = 0.f, s3 = 0.f;
#pragma unroll
        for (int d0 = 0; d0 < 64; d0 += 4) {
            float4 qv = *(const float4*)&Ql[ty][d0];
            float4 k0v = *(const float4*)&Kl[tx     ][d0];
            float4 k1v = *(const float4*)&Kl[tx + 16][d0];
            float4 k2v = *(const float4*)&Kl[tx + 32][d0];
            float4 k3v = *(const float4*)&Kl[tx + 48][d0];
            s0 += qv.x*k0v.x + qv.y*k0v.y + qv.z*k0v.z + qv.w*k0v.w;
            s1 += qv.x*k1v.x + qv.y*k1v.y + qv.z*k1v.z + qv.w*k1v.w;
            s2 += qv.x*k2v.x + qv.y*k2v.y + qv.z*k2v.z + qv.w*k2v.w;
            s3 += qv.x*k3v.x + qv.y*k3v.y + qv.z*k3v.z + qv.w*k3v.w;
        }
        s0 = s0 * 0.125f + btab[k0 + tx];
        s1 = s1 * 0.125f + btab[k0 + tx + 16];
        s2 = s2 * 0.125f + btab[k0 + tx + 32];
        s3 = s3 * 0.125f + btab[k0 + tx + 48];
        if (mrow[k0 + tx     ] == 0) s0 = -1e9f;
        if (mrow[k0 + tx + 16] == 0) s1 = -1e9f;
        if (mrow[k0 + tx + 32] == 0) s2 = -1e9f;
        if (mrow[k0 + tx + 48] == 0) s3 = -1e9f;

        float rowmax = fmaxf(fmaxf(s0, s1), fmaxf(s2, s3));
#pragma unroll
        for (int off = 1; off < 16; off <<= 1)
            rowmax = fmaxf(rowmax, __shfl_xor(rowmax, off, 16));
        float mnew = fmaxf(m, rowmax);
        float scale = expf(m - mnew);          // 0 on first tile (m=-inf)
        float p0 = expf(s0 - mnew), p1 = expf(s1 - mnew);
        float p2 = expf(s2 - mnew), p3 = expf(s3 - mnew);
        float rs = p0 + p1 + p2 + p3;
#pragma unroll
        for (int off = 1; off < 16; off <<= 1)
            rs += __shfl_xor(rs, off, 16);
        l = l * scale + rs;
        m = mnew;
        o0 *= scale; o1 *= scale; o2 *= scale; o3 *= scale;
        Pl[ty][tx     ] = p0;
        Pl[ty][tx + 16] = p1;
        Pl[ty][tx + 32] = p2;
        Pl[ty][tx + 48] = p3;
        __syncthreads();

        // O += P @ V ; thread owns O[ty][tx*4 .. +3]
#pragma unroll 8
        for (int j = 0; j < 64; ++j) {
            float pv = Pl[ty][j];
            float4 v = *(const float4*)&Vl[j][tx * 4];
            o0 += pv * v.x; o1 += pv * v.y; o2 += pv * v.z; o3 += pv * v.w;
        }
        __syncthreads();
    }

    float inv = 1.f / l;
    float4 ov = make_float4(o0 * inv, o1 * inv, o2 * inv, o3 * inv);
    *(float4*)(attnout + ((size_t)((b * HH + h) * TT + q0 + ty) << 6) + tx * 4) = ov;
}

// ---------------------------------------------------------------------------
extern "C" void kernel_launch(void* const* d_in, const int* in_sizes, int n_in,
                              void* d_out, int out_size, void* d_ws, size_t ws_size,
                              hipStream_t stream) {
    const float* q        = (const float*)d_in[0];
    const float* k        = (const float*)d_in[1];
    const float* v        = (const float*)d_in[2];
    const int*   mask     = (const int*)  d_in[3];
    const float* Wq       = (const float*)d_in[4];
    const float* Wk       = (const float*)d_in[5];
    const float* Wv       = (const float*)d_in[6];
    const float* Wfc      = (const float*)d_in[7];
    const float* rel_bias = (const float*)d_in[8];

    float* out0 = (float*)d_out;                       // [B][T][1024]
    float* out1 = out0 + (size_t)BB * TT * DMODEL;     // [H][T][T]

    float* ws    = (float*)d_ws;                       // needs ~50.6 MB
    float* qhp   = ws;                                 // [B][H][T][64]
    float* khp   = ws + (size_t)PSZ;
    float* vhp   = ws + (size_t)2 * PSZ;
    float* btable = ws + (size_t)3 * PSZ;              // [16][4095]

    bias_table_kernel<<<dim3((HH * NREL + 255) / 256), dim3(256), 0, stream>>>(rel_bias, btable);

    dim3 gg(64, 16), gb(256);
    gemm64<0, 1><<<gg, gb, 0, stream>>>(q, Wq, qhp);
    gemm64<0, 1><<<gg, gb, 0, stream>>>(k, Wk, khp);
    gemm64<0, 1><<<gg, gb, 0, stream>>>(v, Wv, vhp);

    bias_write_kernel<<<dim3(2048), dim3(256), 0, stream>>>(btable, out1);

    attn_kernel<<<dim3(BB * HH * (TT / 16)), dim3(256), 0, stream>>>(
        qhp, khp, vhp, mask, btable, qhp);

    gemm64<1, 0><<<gg, gb, 0, stream>>>(qhp, Wfc, out0);
}

// Round 2
// 731.229 us; speedup vs baseline: 1.9469x; 1.9469x over previous
//
#include <hip/hip_runtime.h>
#include <math.h>

#define TT 2048
#define BB 2
#define HH 16
#define DMODEL 1024
#define NREL 4095                      // 2*TT-1
#define PSZ (BB * HH * TT * 64)        // 4194304 elems per projection

typedef __attribute__((ext_vector_type(8)))  _Float16 half8;
typedef __attribute__((ext_vector_type(4)))  _Float16 half4;
typedef __attribute__((ext_vector_type(16))) float    f32x16;
typedef __attribute__((ext_vector_type(4)))  int      int4v;

__device__ __forceinline__ f32x16 zero16() {
    f32x16 v;
#pragma unroll
    for (int i = 0; i < 16; ++i) v[i] = 0.f;
    return v;
}

__device__ __forceinline__ unsigned pkh(float a, float b) {
    union { _Float16 h[2]; unsigned u; } x;
    x.h[0] = (_Float16)a; x.h[1] = (_Float16)b;
    return x.u;
}

// ---------------- bucket (exact-integer replication of reference log math) ---
__device__ __forceinline__ int rel_bucket(int rel) {
    int base = rel > 0 ? 16 : 0;
    int r = rel < 0 ? -rel : rel;
    int lb;
    if (r < 8)       lb = r;
    else if (r < 12) lb = 8;
    else if (r < 16) lb = 9;
    else if (r < 23) lb = 10;
    else if (r < 32) lb = 11;
    else if (r < 46) lb = 12;
    else if (r < 64) lb = 13;
    else if (r < 91) lb = 14;
    else             lb = 15;
    return base + lb;
}

__global__ void bias_table_kernel(const float* __restrict__ rel_bias,
                                  float* __restrict__ btable) {
    int idx = blockIdx.x * blockDim.x + threadIdx.x;
    if (idx >= HH * NREL) return;
    int h = idx / NREL, ri = idx % NREL;
    int bucket = rel_bucket(ri - (TT - 1));
    btable[idx] = rel_bias[bucket * HH + h];   // rel_bias is [32][16]
}

// ---------------- expand bias table to output 1: [H][T][T] -------------------
__global__ void bias_write_kernel(const float* __restrict__ btable,
                                  float* __restrict__ out1) {
    int n4 = HH * TT * TT / 4;
    int stride = gridDim.x * blockDim.x;
    for (int i4 = blockIdx.x * blockDim.x + threadIdx.x; i4 < n4; i4 += stride) {
        int i = i4 * 4;
        int k = i & (TT - 1);
        int q = (i >> 11) & (TT - 1);
        int h = i >> 22;
        const float* bt = btable + h * NREL + (k - q + (TT - 1));
        float4 v = make_float4(bt[0], bt[1], bt[2], bt[3]);
        reinterpret_cast<float4*>(out1)[i4] = v;
    }
}

// ---------------- mask -> bitmask [B][T][64 words] ---------------------------
__global__ void maskpack_kernel(const int* __restrict__ mask,
                                unsigned* __restrict__ mb) {
    int g = blockIdx.x * 256 + threadIdx.x;     // B*T*T threads
    int v = mask[g];
    unsigned long long bal = __ballot(v != 0);
    if ((g & 63) == 0) {
        int word = g >> 5;
        mb[word]     = (unsigned)bal;
        mb[word + 1] = (unsigned)(bal >> 32);
    }
}

// ---------------- f32 tiled GEMM: C(MxN) = A(MxK) @ W(KxN) -------------------
// AMODE 0: A row-major [4096][1024].  AMODE 2: A = [B][H][64][T] f32 (attnT).
// CMODE 0: C f32 row-major.  CMODE 3: C f16 [B][H][T][64].  CMODE 4: C f16 [B][H][64][T].
template<int AMODE, int CMODE>
__global__ __launch_bounds__(256) void gemm64(const float* __restrict__ A,
                                              const float* __restrict__ W,
                                              void* __restrict__ Cout) {
    const int K = DMODEL, N = DMODEL;
    __shared__ float Al[64][20];
    __shared__ float Wl[16][68];
    int bm = blockIdx.x * 64;
    int bn = blockIdx.y * 64;
    int tid = threadIdx.x;
    int ty = tid >> 4, tx = tid & 15;
    int lrow = tid >> 2;            // 0..63
    int lk   = (tid & 3) << 2;      // 0,4,8,12
    int wr   = tid >> 4;
    int wc   = (tid & 15) << 4 >> 2; // (tid&15)*4
    float acc[4][4] = {{0.f}};
    for (int k0 = 0; k0 < K; k0 += 16) {
        int gr = bm + lrow;
        int col = k0 + lk;
        if (AMODE == 0) {
            float4 av = *(const float4*)(A + (size_t)gr * K + col);
            *(float4*)&Al[lrow][lk] = av;
        } else {
            int bb = gr >> 11, t = gr & (TT - 1);
            int hh2 = col >> 6, d = col & 63;
            const float* ap = A + ((size_t)((bb * HH + hh2) * 64 + d)) * TT + t;
            Al[lrow][lk + 0] = ap[0];
            Al[lrow][lk + 1] = ap[TT];
            Al[lrow][lk + 2] = ap[2 * TT];
            Al[lrow][lk + 3] = ap[3 * TT];
        }
        float4 wv = *(const float4*)(W + (size_t)(k0 + wr) * N + bn + wc);
        *(float4*)&Wl[wr][wc] = wv;
        __syncthreads();
#pragma unroll
        for (int kk = 0; kk < 16; ++kk) {
            float a0 = Al[ty*4+0][kk], a1 = Al[ty*4+1][kk];
            float a2 = Al[ty*4+2][kk], a3 = Al[ty*4+3][kk];
            float b0 = Wl[kk][tx*4+0], b1 = Wl[kk][tx*4+1];
            float b2 = Wl[kk][tx*4+2], b3 = Wl[kk][tx*4+3];
            acc[0][0] += a0*b0; acc[0][1] += a0*b1; acc[0][2] += a0*b2; acc[0][3] += a0*b3;
            acc[1][0] += a1*b0; acc[1][1] += a1*b1; acc[1][2] += a1*b2; acc[1][3] += a1*b3;
            acc[2][0] += a2*b0; acc[2][1] += a2*b1; acc[2][2] += a2*b2; acc[2][3] += a2*b3;
            acc[3][0] += a3*b0; acc[3][1] += a3*b1; acc[3][2] += a3*b2; acc[3][3] += a3*b3;
        }
        __syncthreads();
    }
    if (CMODE == 0) {
        float* C = (float*)Cout;
#pragma unroll
        for (int i = 0; i < 4; ++i) {
            int r = bm + ty*4 + i;
            float4 cv = make_float4(acc[i][0], acc[i][1], acc[i][2], acc[i][3]);
            *(float4*)(C + (size_t)r * N + bn + tx*4) = cv;
        }
    } else if (CMODE == 3) {
        _Float16* C = (_Float16*)Cout;
        int n = bn + tx*4, hh2 = n >> 6, d = n & 63;
#pragma unroll
        for (int i = 0; i < 4; ++i) {
            int r = bm + ty*4 + i;
            int bb = r >> 11, t = r & (TT - 1);
            half4 hv = {(_Float16)acc[i][0], (_Float16)acc[i][1],
                        (_Float16)acc[i][2], (_Float16)acc[i][3]};
            *(half4*)(C + ((size_t)((bb * HH + hh2) * TT + t)) * 64 + d) = hv;
        }
    } else {
        _Float16* C = (_Float16*)Cout;
        int t0 = (bm & (TT - 1)) + ty*4;
        int bb = bm >> 11;
#pragma unroll
        for (int jj = 0; jj < 4; ++jj) {
            int n = bn + tx*4 + jj, hh2 = n >> 6, d = n & 63;
            half4 hv = {(_Float16)acc[0][jj], (_Float16)acc[1][jj],
                        (_Float16)acc[2][jj], (_Float16)acc[3][jj]};
            *(half4*)(C + ((size_t)((bb * HH + hh2) * 64 + d)) * TT + t0) = hv;
        }
    }
}

// ---------------- MFMA flash attention (fp16, swapped S^T / O^T) -------------
// grid 512 blocks x 256 thr; wave w handles 32 q-rows; no LDS, no barriers.
__global__ __launch_bounds__(256) void attn_mfma(
    const _Float16* __restrict__ qh, const _Float16* __restrict__ kh,
    const _Float16* __restrict__ vt, const unsigned* __restrict__ maskbits,
    const float* __restrict__ btable, float* __restrict__ attnT)
{
    int bid = blockIdx.x;
    int xcd = bid & 7, j = bid >> 3;
    int qt = j & 15, bh = xcd + 8 * (j >> 4);   // keep one (b,h) per XCD chunk
    int h = bh & 15, b = bh >> 4;
    int tid = threadIdx.x;
    int wv = tid >> 6, lane = tid & 63, lo = lane & 31, hi = lane >> 5;
    int q0 = qt * 128 + wv * 32;

    const size_t bhoff = (size_t)(b * HH + h);
    const _Float16* Q = qh + (bhoff * TT + q0) * 64;
    const _Float16* K = kh + bhoff * TT * 64;
    const _Float16* V = vt + bhoff * 64 * TT;

    half8 qf[4];
#pragma unroll
    for (int c = 0; c < 4; ++c)
        qf[c] = *(const half8*)(Q + (size_t)lo * 64 + c * 16 + hi * 8);

    const float* bt = btable + h * NREL + (TT - 1) - (q0 + lo) + 4 * hi;
    const unsigned* mw = maskbits + ((size_t)b * TT + q0 + lo) * 64;

    f32x16 acco0 = zero16(), acco1 = zero16();
    float m = -INFINITY, l = 0.f;

    for (int kt = 0; kt < TT / 64; ++kt) {
        int k0 = kt * 64;
        half8 kf[2][4], vf[2][4];
#pragma unroll
        for (int g = 0; g < 2; ++g)
#pragma unroll
            for (int c = 0; c < 4; ++c)
                kf[g][c] = *(const half8*)(K + (size_t)(k0 + 32*g + lo) * 64 + c*16 + hi*8);
        unsigned wm0 = mw[2*kt], wm1 = mw[2*kt + 1];
#pragma unroll
        for (int dg = 0; dg < 2; ++dg)
#pragma unroll
            for (int c = 0; c < 4; ++c)
                vf[dg][c] = *(const half8*)(V + (size_t)(32*dg + lo) * TT + k0 + c*16 + hi*8);
        float bias[2][16];
#pragma unroll
        for (int g = 0; g < 2; ++g)
#pragma unroll
            for (int r = 0; r < 16; ++r)
                bias[g][r] = bt[k0 + (r & 3) + 8 * (r >> 2) + 32 * g];

        // S^T = K · Q^T   (rows = keys, cols = q)
        f32x16 accs0 = zero16(), accs1 = zero16();
#pragma unroll
        for (int c = 0; c < 4; ++c) {
            accs0 = __builtin_amdgcn_mfma_f32_32x32x16_f16(kf[0][c], qf[c], accs0, 0, 0, 0);
            accs1 = __builtin_amdgcn_mfma_f32_32x32x16_f16(kf[1][c], qf[c], accs1, 0, 0, 0);
        }

        float p[2][16];
        unsigned ws0 = wm0 >> (hi * 4), ws1 = wm1 >> (hi * 4);
#pragma unroll
        for (int r = 0; r < 16; ++r) {
            int sh = (r & 3) + 8 * (r >> 2);
            float s0 = fmaf(accs0[r], 0.125f, bias[0][r]);
            float s1 = fmaf(accs1[r], 0.125f, bias[1][r]);
            p[0][r] = ((ws0 >> sh) & 1) ? s0 : -1e9f;
            p[1][r] = ((ws1 >> sh) & 1) ? s1 : -1e9f;
        }

        float tm = p[0][0];
#pragma unroll
        for (int g = 0; g < 2; ++g)
#pragma unroll
            for (int r = 0; r < 16; ++r) tm = fmaxf(tm, p[g][r]);
        tm = fmaxf(tm, __shfl_xor(tm, 32));
        float mnew = fmaxf(m, tm);
        float corr = __expf(m - mnew);
        float rs = 0.f;
#pragma unroll
        for (int g = 0; g < 2; ++g)
#pragma unroll
            for (int r = 0; r < 16; ++r) {
                p[g][r] = __expf(p[g][r] - mnew);
                rs += p[g][r];
            }
        rs += __shfl_xor(rs, 32);
        l = l * corr + rs; m = mnew;
#pragma unroll
        for (int r = 0; r < 16; ++r) { acco0[r] *= corr; acco1[r] *= corr; }

        // P^T fragments (B-operand), fully in-register via permlane32_swap
        half8 pb[4];
#pragma unroll
        for (int g = 0; g < 2; ++g)
#pragma unroll
            for (int hc = 0; hc < 2; ++hc) {
                int r0 = hc * 8;
                unsigned w0 = pkh(p[g][r0 + 0], p[g][r0 + 1]);
                unsigned w2 = pkh(p[g][r0 + 4], p[g][r0 + 5]);
                asm("v_permlane32_swap_b32 %0, %1" : "+v"(w0), "+v"(w2));
                unsigned w1 = pkh(p[g][r0 + 2], p[g][r0 + 3]);
                unsigned w3 = pkh(p[g][r0 + 6], p[g][r0 + 7]);
                asm("v_permlane32_swap_b32 %0, %1" : "+v"(w1), "+v"(w3));
                union { int4v i; half8 hf; } cv;
                cv.i = (int4v){(int)w0, (int)w1, (int)w2, (int)w3};
                pb[2 * g + hc] = cv.hf;
            }

        // O^T += V^T · P^T
#pragma unroll
        for (int c = 0; c < 4; ++c) {
            acco0 = __builtin_amdgcn_mfma_f32_32x32x16_f16(vf[0][c], pb[c], acco0, 0, 0, 0);
            acco1 = __builtin_amdgcn_mfma_f32_32x32x16_f16(vf[1][c], pb[c], acco1, 0, 0, 0);
        }
    }

    float inv = 1.f / l;
    float* op = attnT + (bhoff * 64) * TT + q0 + lo;
#pragma unroll
    for (int r = 0; r < 16; ++r) {
        int row = (r & 3) + 8 * (r >> 2) + 4 * hi;
        op[(size_t)row * TT]        = acco0[r] * inv;
        op[(size_t)(row + 32) * TT] = acco1[r] * inv;
    }
}

// ---------------------------------------------------------------------------
extern "C" void kernel_launch(void* const* d_in, const int* in_sizes, int n_in,
                              void* d_out, int out_size, void* d_ws, size_t ws_size,
                              hipStream_t stream) {
    const float* q        = (const float*)d_in[0];
    const float* k        = (const float*)d_in[1];
    const float* v        = (const float*)d_in[2];
    const int*   mask     = (const int*)  d_in[3];
    const float* Wq       = (const float*)d_in[4];
    const float* Wk       = (const float*)d_in[5];
    const float* Wv       = (const float*)d_in[6];
    const float* Wfc      = (const float*)d_in[7];
    const float* rel_bias = (const float*)d_in[8];

    float* out0 = (float*)d_out;                       // [B][T][1024]
    float* out1 = out0 + (size_t)BB * TT * DMODEL;     // [H][T][T]

    char* w = (char*)d_ws;
    _Float16* qhf   = (_Float16*)w;                            // 8 MB
    _Float16* khf   = (_Float16*)(w + (size_t)PSZ * 2);        // 8 MB
    _Float16* vtf   = (_Float16*)(w + (size_t)PSZ * 4);        // 8 MB [B][H][64][T]
    float*    attnT = (float*)   (w + (size_t)PSZ * 6);        // 16 MB [B][H][64][T]
    float*    btable= (float*)   (w + (size_t)PSZ * 10);       // 262 KB
    unsigned* mbits = (unsigned*)(w + (size_t)PSZ * 10 + 0x80000); // 1 MB

    bias_table_kernel<<<dim3((HH * NREL + 255) / 256), dim3(256), 0, stream>>>(rel_bias, btable);
    maskpack_kernel<<<dim3(BB * TT * TT / 256), dim3(256), 0, stream>>>(mask, mbits);

    dim3 gg(64, 16), gb(256);
    gemm64<0, 3><<<gg, gb, 0, stream>>>(q, Wq, qhf);
    gemm64<0, 3><<<gg, gb, 0, stream>>>(k, Wk, khf);
    gemm64<0, 4><<<gg, gb, 0, stream>>>(v, Wv, vtf);

    bias_write_kernel<<<dim3(2048), dim3(256), 0, stream>>>(btable, out1);

    attn_mfma<<<dim3(BB * HH * 16), dim3(256), 0, stream>>>(
        qhf, khf, vtf, mbits, btable, attnT);

    gemm64<2, 0><<<gg, gb, 0, stream>>>(attnT, Wfc, out0);
}

// Round 3
// 302.759 us; speedup vs baseline: 4.7021x; 2.4152x over previous
//
#include <hip/hip_runtime.h>
#include <math.h>

#define TT 2048
#define BB 2
#define HH 16
#define DMODEL 1024
#define NREL 4095                      // 2*TT-1

typedef __attribute__((ext_vector_type(8)))  _Float16 half8;
typedef __attribute__((ext_vector_type(4)))  _Float16 half4;
typedef __attribute__((ext_vector_type(16))) float    f32x16;
typedef __attribute__((ext_vector_type(4)))  int      int4v;

__device__ __forceinline__ f32x16 zero16() {
    f32x16 v;
#pragma unroll
    for (int i = 0; i < 16; ++i) v[i] = 0.f;
    return v;
}

__device__ __forceinline__ unsigned pkh(float a, float b) {
    union { _Float16 h[2]; unsigned u; } x;
    x.h[0] = (_Float16)a; x.h[1] = (_Float16)b;
    return x.u;
}

// ---------------- bucket (exact-integer replication of reference log math) ---
__device__ __forceinline__ int rel_bucket(int rel) {
    int base = rel > 0 ? 16 : 0;
    int r = rel < 0 ? -rel : rel;
    int lb;
    if (r < 8)       lb = r;
    else if (r < 12) lb = 8;
    else if (r < 16) lb = 9;
    else if (r < 23) lb = 10;
    else if (r < 32) lb = 11;
    else if (r < 46) lb = 12;
    else if (r < 64) lb = 13;
    else if (r < 91) lb = 14;
    else             lb = 15;
    return base + lb;
}

__global__ void bias_table_kernel(const float* __restrict__ rel_bias,
                                  float* __restrict__ btable) {
    int idx = blockIdx.x * blockDim.x + threadIdx.x;
    if (idx >= HH * NREL) return;
    int h = idx / NREL, ri = idx % NREL;
    int bucket = rel_bucket(ri - (TT - 1));
    btable[idx] = rel_bias[bucket * HH + h];   // rel_bias is [32][16]
}

// ---------------- expand bias table to output 1: [H][T][T] -------------------
__global__ void bias_write_kernel(const float* __restrict__ btable,
                                  float* __restrict__ out1) {
    int n4 = HH * TT * TT / 4;
    int stride = gridDim.x * blockDim.x;
    for (int i4 = blockIdx.x * blockDim.x + threadIdx.x; i4 < n4; i4 += stride) {
        int i = i4 * 4;
        int k = i & (TT - 1);
        int q = (i >> 11) & (TT - 1);
        int h = i >> 22;
        const float* bt = btable + h * NREL + (k - q + (TT - 1));
        float4 v = make_float4(bt[0], bt[1], bt[2], bt[3]);
        reinterpret_cast<float4*>(out1)[i4] = v;
    }
}

// ---------------- mask -> bitmask [B][T][64 words] ---------------------------
__global__ void maskpack_kernel(const int* __restrict__ mask,
                                unsigned* __restrict__ mb) {
    int g = blockIdx.x * 256 + threadIdx.x;     // B*T*T threads
    int v = mask[g];
    unsigned long long bal = __ballot(v != 0);
    if ((g & 63) == 0) {
        int word = g >> 5;
        mb[word]     = (unsigned)bal;
        mb[word + 1] = (unsigned)(bal >> 32);
    }
}

// ---------------- f32 -> f16 convert (row-major preserved) -------------------
__global__ void cvt16_kernel(const float* __restrict__ in, _Float16* __restrict__ out) {
    int i = blockIdx.x * 256 + threadIdx.x;    // 8 elems per thread
    const float4* in4 = (const float4*)in;
    float4 v0 = in4[(size_t)i * 2], v1 = in4[(size_t)i * 2 + 1];
    half8 h = {(_Float16)v0.x, (_Float16)v0.y, (_Float16)v0.z, (_Float16)v0.w,
               (_Float16)v1.x, (_Float16)v1.y, (_Float16)v1.z, (_Float16)v1.w};
    *(half8*)(out + (size_t)i * 8) = h;
}

// ---------------- W [k][n] f32 -> WT [n][k] f16 ------------------------------
__global__ __launch_bounds__(256) void wtrans_kernel(const float* __restrict__ W0,
                                                     const float* __restrict__ W1,
                                                     const float* __restrict__ W2,
                                                     const float* __restrict__ W3,
                                                     _Float16* __restrict__ out) {
    int z = blockIdx.z;
    const float* src = z == 0 ? W0 : z == 1 ? W1 : z == 2 ? W2 : W3;
    _Float16* dst = out + (size_t)z * DMODEL * DMODEL;
    __shared__ float t[64][65];
    int k0 = blockIdx.x * 64, n0 = blockIdx.y * 64;
    int tid = threadIdx.x;
    int r = tid >> 4, c4 = (tid & 15) * 4;
#pragma unroll
    for (int i = 0; i < 4; ++i) {
        float4 v = *(const float4*)(src + (size_t)(k0 + r + 16 * i) * DMODEL + n0 + c4);
        t[r + 16 * i][c4] = v.x; t[r + 16 * i][c4 + 1] = v.y;
        t[r + 16 * i][c4 + 2] = v.z; t[r + 16 * i][c4 + 3] = v.w;
    }
    __syncthreads();
    int rn = tid >> 2, ck = (tid & 3) * 16;
    half8 h0, h1;
#pragma unroll
    for (int j = 0; j < 8; ++j) h0[j] = (_Float16)t[ck + j][rn];
#pragma unroll
    for (int j = 0; j < 8; ++j) h1[j] = (_Float16)t[ck + 8 + j][rn];
    *(half8*)(dst + (size_t)(n0 + rn) * DMODEL + k0 + ck) = h0;
    *(half8*)(dst + (size_t)(n0 + rn) * DMODEL + k0 + ck + 8) = h1;
}

// ---------------- fused projection MFMA GEMM (z: 0=q,1=k,2=v) ----------------
// A f16 row-major [4096][1024]; Bt = WT[n][k]; 128x128 tile, BK=64.
// z<2 -> C f16 [B][H][T][64]; z==2 -> C f16 [B][H][64][T] (transposed).
__global__ __launch_bounds__(256, 3) void gemm_proj3(
    const _Float16* __restrict__ q16, const _Float16* __restrict__ k16,
    const _Float16* __restrict__ v16, const _Float16* __restrict__ WT,
    _Float16* __restrict__ qhf, _Float16* __restrict__ khf,
    _Float16* __restrict__ vtf, int zbase)
{
    __shared__ char lds[32768];
    int z = zbase + blockIdx.z;
    const _Float16* A  = z == 0 ? q16 : z == 1 ? k16 : v16;
    const _Float16* Bt = WT + (size_t)z * DMODEL * DMODEL;
    int bm = blockIdx.x * 128, bn = blockIdx.y * 128;
    int tid = threadIdx.x;
    int wv = tid >> 6, lane = tid & 63, lo = lane & 31, hi = lane >> 5;
    int wr = wv >> 1, wc = wv & 1;
    int r0 = tid >> 3, s = tid & 7;

    const _Float16* ap[4]; const _Float16* bp[4];
    int awo[4], bwo[4];
#pragma unroll
    for (int c = 0; c < 4; ++c) {
        int r = r0 + 32 * c;
        ap[c] = A  + (size_t)(bm + r) * DMODEL + s * 8;
        bp[c] = Bt + (size_t)(bn + r) * DMODEL + s * 8;
        awo[c] = r * 128 + ((s ^ (r & 7)) << 4);
        bwo[c] = 16384 + r * 128 + ((s ^ (r & 7)) << 4);
    }

    f32x16 acc[2][2];
    acc[0][0] = zero16(); acc[0][1] = zero16();
    acc[1][0] = zero16(); acc[1][1] = zero16();

    half8 pa[4], pb[4];
#pragma unroll
    for (int c = 0; c < 4; ++c) { pa[c] = *(const half8*)ap[c]; pb[c] = *(const half8*)bp[c]; }

    for (int kt = 0; kt < 16; ++kt) {
        __syncthreads();
#pragma unroll
        for (int c = 0; c < 4; ++c) {
            *(half8*)(lds + awo[c]) = pa[c];
            *(half8*)(lds + bwo[c]) = pb[c];
        }
        __syncthreads();
        if (kt < 15) {
#pragma unroll
            for (int c = 0; c < 4; ++c) {
                pa[c] = *(const half8*)(ap[c] + (kt + 1) * 64);
                pb[c] = *(const half8*)(bp[c] + (kt + 1) * 64);
            }
        }
#pragma unroll
        for (int k = 0; k < 4; ++k) {
            int cs = 2 * k + hi;
            half8 a[2], b[2];
#pragma unroll
            for (int i = 0; i < 2; ++i) {
                int ra = wr * 64 + i * 32 + lo;
                a[i] = *(const half8*)(lds + ra * 128 + ((cs ^ (ra & 7)) << 4));
                int rb = wc * 64 + i * 32 + lo;
                b[i] = *(const half8*)(lds + 16384 + rb * 128 + ((cs ^ (rb & 7)) << 4));
            }
            acc[0][0] = __builtin_amdgcn_mfma_f32_32x32x16_f16(a[0], b[0], acc[0][0], 0, 0, 0);
            acc[0][1] = __builtin_amdgcn_mfma_f32_32x32x16_f16(a[0], b[1], acc[0][1], 0, 0, 0);
            acc[1][0] = __builtin_amdgcn_mfma_f32_32x32x16_f16(a[1], b[0], acc[1][0], 0, 0, 0);
            acc[1][1] = __builtin_amdgcn_mfma_f32_32x32x16_f16(a[1], b[1], acc[1][1], 0, 0, 0);
        }
    }

    if (z < 2) {
        _Float16* C = z == 0 ? qhf : khf;
#pragma unroll
        for (int j = 0; j < 2; ++j) {
            int n = bn + wc * 64 + j * 32 + lo;
            int h = n >> 6, d = n & 63;
#pragma unroll
            for (int i = 0; i < 2; ++i) {
                int mb = bm + wr * 64 + i * 32 + 4 * hi;
#pragma unroll
                for (int r = 0; r < 16; ++r) {
                    int m = mb + (r & 3) + 8 * (r >> 2);
                    int b = m >> 11, t = m & (TT - 1);
                    C[((size_t)(b * HH + h) * TT + t) * 64 + d] = (_Float16)acc[i][j][r];
                }
            }
        }
    } else {
#pragma unroll
        for (int j = 0; j < 2; ++j) {
            int n = bn + wc * 64 + j * 32 + lo;
            int h = n >> 6, d = n & 63;
#pragma unroll
            for (int i = 0; i < 2; ++i) {
                int mb = bm + wr * 64 + i * 32 + 4 * hi;
                int b = mb >> 11, tb = mb & (TT - 1);
#pragma unroll
                for (int r4 = 0; r4 < 4; ++r4) {
                    half4 hv = {(_Float16)acc[i][j][4 * r4 + 0], (_Float16)acc[i][j][4 * r4 + 1],
                                (_Float16)acc[i][j][4 * r4 + 2], (_Float16)acc[i][j][4 * r4 + 3]};
                    *(half4*)(vtf + ((size_t)(b * HH + h) * 64 + d) * TT + tb + 8 * r4) = hv;
                }
            }
        }
    }
}

// ---------------- fc MFMA GEMM: out0 = O @ Wfc -------------------------------
// A = O f16 [B][H][T][64]; Bt = WTfc[n][k]; C = f32 row-major [4096][1024].
__global__ __launch_bounds__(256, 3) void gemm_fc(
    const _Float16* __restrict__ O, const _Float16* __restrict__ Bt,
    float* __restrict__ out0)
{
    __shared__ char lds[32768];
    int bm = blockIdx.x * 128, bn = blockIdx.y * 128;
    int tid = threadIdx.x;
    int wv = tid >> 6, lane = tid & 63, lo = lane & 31, hi = lane >> 5;
    int wr = wv >> 1, wc = wv & 1;
    int r0 = tid >> 3, s = tid & 7;
    int bb = bm >> 11, tbase = bm & (TT - 1);

    const _Float16* ap[4]; const _Float16* bp[4];
    int awo[4], bwo[4];
#pragma unroll
    for (int c = 0; c < 4; ++c) {
        int r = r0 + 32 * c;
        ap[c] = O  + ((size_t)(bb * HH) * TT + tbase + r) * 64 + s * 8;   // head 0
        bp[c] = Bt + (size_t)(bn + r) * DMODEL + s * 8;
        awo[c] = r * 128 + ((s ^ (r & 7)) << 4);
        bwo[c] = 16384 + r * 128 + ((s ^ (r & 7)) << 4);
    }

    f32x16 acc[2][2];
    acc[0][0] = zero16(); acc[0][1] = zero16();
    acc[1][0] = zero16(); acc[1][1] = zero16();

    half8 pa[4], pb[4];
#pragma unroll
    for (int c = 0; c < 4; ++c) { pa[c] = *(const half8*)ap[c]; pb[c] = *(const half8*)bp[c]; }

    for (int kt = 0; kt < 16; ++kt) {
        __syncthreads();
#pragma unroll
        for (int c = 0; c < 4; ++c) {
            *(half8*)(lds + awo[c]) = pa[c];
            *(half8*)(lds + bwo[c]) = pb[c];
        }
        __syncthreads();
        if (kt < 15) {
#pragma unroll
            for (int c = 0; c < 4; ++c) {
                pa[c] = *(const half8*)(ap[c] + (size_t)(kt + 1) * TT * 64);
                pb[c] = *(const half8*)(bp[c] + (kt + 1) * 64);
            }
        }
#pragma unroll
        for (int k = 0; k < 4; ++k) {
            int cs = 2 * k + hi;
            half8 a[2], b[2];
#pragma unroll
            for (int i = 0; i < 2; ++i) {
                int ra = wr * 64 + i * 32 + lo;
                a[i] = *(const half8*)(lds + ra * 128 + ((cs ^ (ra & 7)) << 4));
                int rb = wc * 64 + i * 32 + lo;
                b[i] = *(const half8*)(lds + 16384 + rb * 128 + ((cs ^ (rb & 7)) << 4));
            }
            acc[0][0] = __builtin_amdgcn_mfma_f32_32x32x16_f16(a[0], b[0], acc[0][0], 0, 0, 0);
            acc[0][1] = __builtin_amdgcn_mfma_f32_32x32x16_f16(a[0], b[1], acc[0][1], 0, 0, 0);
            acc[1][0] = __builtin_amdgcn_mfma_f32_32x32x16_f16(a[1], b[0], acc[1][0], 0, 0, 0);
            acc[1][1] = __builtin_amdgcn_mfma_f32_32x32x16_f16(a[1], b[1], acc[1][1], 0, 0, 0);
        }
    }

#pragma unroll
    for (int j = 0; j < 2; ++j) {
        int n = bn + wc * 64 + j * 32 + lo;
#pragma unroll
        for (int i = 0; i < 2; ++i) {
            int mb = bm + wr * 64 + i * 32 + 4 * hi;
#pragma unroll
            for (int r = 0; r < 16; ++r) {
                int m = mb + (r & 3) + 8 * (r >> 2);
                out0[(size_t)m * DMODEL + n] = acc[i][j][r];
            }
        }
    }
}

// ---------------- MFMA flash attention (fp16, swapped S^T / O^T) -------------
__global__ __launch_bounds__(256) void attn_mfma(
    const _Float16* __restrict__ qh, const _Float16* __restrict__ kh,
    const _Float16* __restrict__ vt, const unsigned* __restrict__ maskbits,
    const float* __restrict__ btable, _Float16* __restrict__ Oout)
{
    int bid = blockIdx.x;
    int xcd = bid & 7, j = bid >> 3;
    int qt = j & 15, bh = xcd + 8 * (j >> 4);
    int h = bh & 15, b = bh >> 4;
    int tid = threadIdx.x;
    int wv = tid >> 6, lane = tid & 63, lo = lane & 31, hi = lane >> 5;
    int q0 = qt * 128 + wv * 32;

    const size_t bhoff = (size_t)(b * HH + h);
    const _Float16* Q = qh + (bhoff * TT + q0) * 64;
    const _Float16* K = kh + bhoff * TT * 64;
    const _Float16* V = vt + bhoff * 64 * TT;

    half8 qf[4];
#pragma unroll
    for (int c = 0; c < 4; ++c)
        qf[c] = *(const half8*)(Q + (size_t)lo * 64 + c * 16 + hi * 8);

    const float* bt = btable + h * NREL + (TT - 1) - (q0 + lo) + 4 * hi;
    const unsigned* mw = maskbits + ((size_t)b * TT + q0 + lo) * 64;

    f32x16 acco0 = zero16(), acco1 = zero16();
    float m = -INFINITY, l = 0.f;

    for (int kt = 0; kt < TT / 64; ++kt) {
        int k0 = kt * 64;
        half8 kf[2][4], vf[2][4];
#pragma unroll
        for (int g = 0; g < 2; ++g)
#pragma unroll
            for (int c = 0; c < 4; ++c)
                kf[g][c] = *(const half8*)(K + (size_t)(k0 + 32 * g + lo) * 64 + c * 16 + hi * 8);
        unsigned wm0 = mw[2 * kt], wm1 = mw[2 * kt + 1];
#pragma unroll
        for (int dg = 0; dg < 2; ++dg)
#pragma unroll
            for (int c = 0; c < 4; ++c)
                vf[dg][c] = *(const half8*)(V + (size_t)(32 * dg + lo) * TT + k0 + c * 16 + hi * 8);
        float bias[2][16];
#pragma unroll
        for (int g = 0; g < 2; ++g)
#pragma unroll
            for (int r = 0; r < 16; ++r)
                bias[g][r] = bt[k0 + (r & 3) + 8 * (r >> 2) + 32 * g];

        f32x16 accs0 = zero16(), accs1 = zero16();
#pragma unroll
        for (int c = 0; c < 4; ++c) {
            accs0 = __builtin_amdgcn_mfma_f32_32x32x16_f16(kf[0][c], qf[c], accs0, 0, 0, 0);
            accs1 = __builtin_amdgcn_mfma_f32_32x32x16_f16(kf[1][c], qf[c], accs1, 0, 0, 0);
        }

        float p[2][16];
        unsigned ws0 = wm0 >> (hi * 4), ws1 = wm1 >> (hi * 4);
#pragma unroll
        for (int r = 0; r < 16; ++r) {
            int sh = (r & 3) + 8 * (r >> 2);
            float s0 = fmaf(accs0[r], 0.125f, bias[0][r]);
            float s1 = fmaf(accs1[r], 0.125f, bias[1][r]);
            p[0][r] = ((ws0 >> sh) & 1) ? s0 : -1e9f;
            p[1][r] = ((ws1 >> sh) & 1) ? s1 : -1e9f;
        }

        float tm = p[0][0];
#pragma unroll
        for (int g = 0; g < 2; ++g)
#pragma unroll
            for (int r = 0; r < 16; ++r) tm = fmaxf(tm, p[g][r]);
        tm = fmaxf(tm, __shfl_xor(tm, 32));
        float mnew = fmaxf(m, tm);
        float corr = __expf(m - mnew);
        float rs = 0.f;
#pragma unroll
        for (int g = 0; g < 2; ++g)
#pragma unroll
            for (int r = 0; r < 16; ++r) {
                p[g][r] = __expf(p[g][r] - mnew);
                rs += p[g][r];
            }
        rs += __shfl_xor(rs, 32);
        l = l * corr + rs; m = mnew;
#pragma unroll
        for (int r = 0; r < 16; ++r) { acco0[r] *= corr; acco1[r] *= corr; }

        half8 pb[4];
#pragma unroll
        for (int g = 0; g < 2; ++g)
#pragma unroll
            for (int hc = 0; hc < 2; ++hc) {
                int r0 = hc * 8;
                unsigned w0 = pkh(p[g][r0 + 0], p[g][r0 + 1]);
                unsigned w2 = pkh(p[g][r0 + 4], p[g][r0 + 5]);
                asm("v_permlane32_swap_b32 %0, %1" : "+v"(w0), "+v"(w2));
                unsigned w1 = pkh(p[g][r0 + 2], p[g][r0 + 3]);
                unsigned w3 = pkh(p[g][r0 + 6], p[g][r0 + 7]);
                asm("v_permlane32_swap_b32 %0, %1" : "+v"(w1), "+v"(w3));
                union { int4v i; half8 hf; } cv;
                cv.i = (int4v){(int)w0, (int)w1, (int)w2, (int)w3};
                pb[2 * g + hc] = cv.hf;
            }

#pragma unroll
        for (int c = 0; c < 4; ++c) {
            acco0 = __builtin_amdgcn_mfma_f32_32x32x16_f16(vf[0][c], pb[c], acco0, 0, 0, 0);
            acco1 = __builtin_amdgcn_mfma_f32_32x32x16_f16(vf[1][c], pb[c], acco1, 0, 0, 0);
        }
    }

    float inv = 1.f / l;
    _Float16* op = Oout + (bhoff * TT + q0 + lo) * 64;
#pragma unroll
    for (int r4 = 0; r4 < 4; ++r4) {
        int d0 = 8 * r4 + 4 * hi;
        half4 h0 = {(_Float16)(acco0[4 * r4 + 0] * inv), (_Float16)(acco0[4 * r4 + 1] * inv),
                    (_Float16)(acco0[4 * r4 + 2] * inv), (_Float16)(acco0[4 * r4 + 3] * inv)};
        *(half4*)(op + d0) = h0;
        half4 h1 = {(_Float16)(acco1[4 * r4 + 0] * inv), (_Float16)(acco1[4 * r4 + 1] * inv),
                    (_Float16)(acco1[4 * r4 + 2] * inv), (_Float16)(acco1[4 * r4 + 3] * inv)};
        *(half4*)(op + d0 + 32) = h1;
    }
}

// ---------------------------------------------------------------------------
extern "C" void kernel_launch(void* const* d_in, const int* in_sizes, int n_in,
                              void* d_out, int out_size, void* d_ws, size_t ws_size,
                              hipStream_t stream) {
    const float* q        = (const float*)d_in[0];
    const float* k        = (const float*)d_in[1];
    const float* v        = (const float*)d_in[2];
    const int*   mask     = (const int*)  d_in[3];
    const float* Wq       = (const float*)d_in[4];
    const float* Wk       = (const float*)d_in[5];
    const float* Wv       = (const float*)d_in[6];
    const float* Wfc      = (const float*)d_in[7];
    const float* rel_bias = (const float*)d_in[8];

    float* out0 = (float*)d_out;                       // [B][T][1024]
    float* out1 = out0 + (size_t)BB * TT * DMODEL;     // [H][T][T]

    char* w = (char*)d_ws;
    _Float16* q16 = (_Float16*)(w);                    // [0,8MB)   later: O
    _Float16* k16 = (_Float16*)(w + ((size_t)8  << 20));
    _Float16* v16 = (_Float16*)(w + ((size_t)16 << 20));
    _Float16* qhf = (_Float16*)(w + ((size_t)24 << 20));
    _Float16* khf = (_Float16*)(w + ((size_t)32 << 20));
    _Float16* WT  = (_Float16*)(w + ((size_t)40 << 20)); // 4 x 2MB
    float*    btable = (float*)(w + ((size_t)48 << 20));
    unsigned* mbits  = (unsigned*)(w + ((size_t)48 << 20) + ((size_t)1 << 19));
    bool big = ws_size >= ((size_t)58 << 20);
    _Float16* vtf = big ? (_Float16*)(w + ((size_t)49 << 20) + ((size_t)1 << 19))
                        : k16;                          // fallback: alias k16
    _Float16* O = q16;

    bias_table_kernel<<<dim3((HH * NREL + 255) / 256), dim3(256), 0, stream>>>(rel_bias, btable);
    maskpack_kernel<<<dim3(BB * TT * TT / 256), dim3(256), 0, stream>>>(mask, mbits);

    cvt16_kernel<<<dim3(2048), dim3(256), 0, stream>>>(q, q16);
    cvt16_kernel<<<dim3(2048), dim3(256), 0, stream>>>(k, k16);
    cvt16_kernel<<<dim3(2048), dim3(256), 0, stream>>>(v, v16);
    wtrans_kernel<<<dim3(16, 16, 4), dim3(256), 0, stream>>>(Wq, Wk, Wv, Wfc, WT);

    if (big) {
        gemm_proj3<<<dim3(32, 8, 3), dim3(256), 0, stream>>>(q16, k16, v16, WT,
                                                             qhf, khf, vtf, 0);
    } else {
        gemm_proj3<<<dim3(32, 8, 1), dim3(256), 0, stream>>>(q16, k16, v16, WT, qhf, khf, vtf, 0);
        gemm_proj3<<<dim3(32, 8, 1), dim3(256), 0, stream>>>(q16, k16, v16, WT, qhf, khf, vtf, 1);
        gemm_proj3<<<dim3(32, 8, 1), dim3(256), 0, stream>>>(q16, k16, v16, WT, qhf, khf, vtf, 2);
    }

    bias_write_kernel<<<dim3(2048), dim3(256), 0, stream>>>(btable, out1);

    attn_mfma<<<dim3(BB * HH * 16), dim3(256), 0, stream>>>(
        qhf, khf, vtf, mbits, btable, O);

    gemm_fc<<<dim3(32, 8), dim3(256), 0, stream>>>(O, WT + (size_t)3 * DMODEL * DMODEL, out0);
}

// Round 4
// 291.228 us; speedup vs baseline: 4.8883x; 1.0396x over previous
//
#include <hip/hip_runtime.h>
#include <math.h>

#define TT 2048
#define BB 2
#define HH 16
#define DMODEL 1024
#define NREL 4095                      // 2*TT-1

typedef __attribute__((ext_vector_type(8)))  _Float16 half8;
typedef __attribute__((ext_vector_type(4)))  _Float16 half4;
typedef __attribute__((ext_vector_type(16))) float    f32x16;
typedef __attribute__((ext_vector_type(4)))  int      int4v;

__device__ __forceinline__ f32x16 zero16() {
    f32x16 v;
#pragma unroll
    for (int i = 0; i < 16; ++i) v[i] = 0.f;
    return v;
}

__device__ __forceinline__ unsigned pkh(float a, float b) {
    union { _Float16 h[2]; unsigned u; } x;
    x.h[0] = (_Float16)a; x.h[1] = (_Float16)b;
    return x.u;
}

// async global->LDS, 16B per lane; LDS dest = wave-uniform base + lane*16
__device__ __forceinline__ void gload16(const void* g, void* l) {
    __builtin_amdgcn_global_load_lds(
        (const __attribute__((address_space(1))) void*)g,
        (__attribute__((address_space(3))) void*)l, 16, 0, 0);
}

// ---------------- bucket (exact-integer replication of reference log math) ---
__device__ __forceinline__ int rel_bucket(int rel) {
    int base = rel > 0 ? 16 : 0;
    int r = rel < 0 ? -rel : rel;
    int lb;
    if (r < 8)       lb = r;
    else if (r < 12) lb = 8;
    else if (r < 16) lb = 9;
    else if (r < 23) lb = 10;
    else if (r < 32) lb = 11;
    else if (r < 46) lb = 12;
    else if (r < 64) lb = 13;
    else if (r < 91) lb = 14;
    else             lb = 15;
    return base + lb;
}

// ---------------- fused prep: bias_table | wtrans | cvt16 x3 | maskpack ------
// blocks: [0,256) bias_table; [256,1280) wtrans; [1280,7424) cvt; [7424,40192) maskpack
__global__ __launch_bounds__(256) void prep_kernel(
    const float* __restrict__ q, const float* __restrict__ k,
    const float* __restrict__ v, const int* __restrict__ mask,
    const float* __restrict__ W0, const float* __restrict__ W1,
    const float* __restrict__ W2, const float* __restrict__ W3,
    const float* __restrict__ rel_bias,
    _Float16* __restrict__ q16, _Float16* __restrict__ k16,
    _Float16* __restrict__ v16, _Float16* __restrict__ WT,
    float* __restrict__ btable, unsigned* __restrict__ mb)
{
    __shared__ float t[64][65];
    int bid = blockIdx.x, tid = threadIdx.x;
    if (bid < 256) {
        int idx = bid * 256 + tid;
        if (idx < HH * NREL) {
            int h = idx / NREL, ri = idx % NREL;
            btable[idx] = rel_bias[rel_bucket(ri - (TT - 1)) * HH + h];
        }
    } else if (bid < 1280) {
        int zz = (bid - 256) >> 8, inner = (bid - 256) & 255;
        const float* src = zz == 0 ? W0 : zz == 1 ? W1 : zz == 2 ? W2 : W3;
        _Float16* dst = WT + (size_t)zz * DMODEL * DMODEL;
        int k0 = (inner >> 4) * 64, n0 = (inner & 15) * 64;
        int r = tid >> 4, c4 = (tid & 15) * 4;
#pragma unroll
        for (int i = 0; i < 4; ++i) {
            float4 vv = *(const float4*)(src + (size_t)(k0 + r + 16 * i) * DMODEL + n0 + c4);
            t[r + 16 * i][c4] = vv.x; t[r + 16 * i][c4 + 1] = vv.y;
            t[r + 16 * i][c4 + 2] = vv.z; t[r + 16 * i][c4 + 3] = vv.w;
        }
        __syncthreads();
        int rn = tid >> 2, ck = (tid & 3) * 16;
        half8 h0, h1;
#pragma unroll
        for (int j = 0; j < 8; ++j) h0[j] = (_Float16)t[ck + j][rn];
#pragma unroll
        for (int j = 0; j < 8; ++j) h1[j] = (_Float16)t[ck + 8 + j][rn];
        *(half8*)(dst + (size_t)(n0 + rn) * DMODEL + k0 + ck) = h0;
        *(half8*)(dst + (size_t)(n0 + rn) * DMODEL + k0 + ck + 8) = h1;
    } else if (bid < 7424) {
        int zz = (bid - 1280) >> 11, inner = (bid - 1280) & 2047;
        const float* src = zz == 0 ? q : zz == 1 ? k : v;
        _Float16* dst = zz == 0 ? q16 : zz == 1 ? k16 : v16;
        int i = inner * 256 + tid;
        const float4* in4 = (const float4*)src;
        float4 v0 = in4[(size_t)i * 2], v1 = in4[(size_t)i * 2 + 1];
        half8 h = {(_Float16)v0.x, (_Float16)v0.y, (_Float16)v0.z, (_Float16)v0.w,
                   (_Float16)v1.x, (_Float16)v1.y, (_Float16)v1.z, (_Float16)v1.w};
        *(half8*)(dst + (size_t)i * 8) = h;
    } else {
        int g = (bid - 7424) * 256 + tid;
        int vv = mask[g];
        unsigned long long bal = __ballot(vv != 0);
        if ((g & 63) == 0) {
            int word = g >> 5;
            mb[word]     = (unsigned)bal;
            mb[word + 1] = (unsigned)(bal >> 32);
        }
    }
}

// ---------------- fused projection MFMA GEMM (z: 0=q,1=k,2=v) ----------------
// A f16 row-major [4096][1024]; Bt = WT[n][k]; 128x128 tile, BK=64, gload_lds.
__global__ __launch_bounds__(256, 4) void gemm_proj3(
    const _Float16* __restrict__ q16, const _Float16* __restrict__ k16,
    const _Float16* __restrict__ v16, const _Float16* __restrict__ WT,
    _Float16* __restrict__ qhf, _Float16* __restrict__ khf,
    _Float16* __restrict__ vtf, int zbase)
{
    __shared__ __align__(16) char lds[32768];   // A [0,16K), B [16K,32K)
    int z = zbase + blockIdx.z;
    const _Float16* A  = z == 0 ? q16 : z == 1 ? k16 : v16;
    const _Float16* Bt = WT + (size_t)z * DMODEL * DMODEL;
    int bm = blockIdx.x * 128, bn = blockIdx.y * 128;
    int tid = threadIdx.x;
    int wv = tid >> 6, lane = tid & 63, lo = lane & 31, hi = lane >> 5;
    int wr = wv >> 1, wc = wv & 1;
    int srow = wv * 32 + (lane >> 3);
    int scol = (lane & 7) * 8;

    f32x16 acc[2][2];
    acc[0][0] = zero16(); acc[0][1] = zero16();
    acc[1][0] = zero16(); acc[1][1] = zero16();

    for (int kt = 0; kt < 16; ++kt) {
#pragma unroll
        for (int t = 0; t < 4; ++t) {
            gload16(A  + (size_t)(bm + srow + t * 8) * DMODEL + kt * 64 + scol,
                    lds + wv * 4096 + t * 1024);
            gload16(Bt + (size_t)(bn + srow + t * 8) * DMODEL + kt * 64 + scol,
                    lds + 16384 + wv * 4096 + t * 1024);
        }
        __syncthreads();
#pragma unroll
        for (int kk = 0; kk < 4; ++kk) {
            int cs = 2 * kk + hi;
            half8 a[2], b[2];
#pragma unroll
            for (int i = 0; i < 2; ++i) {
                a[i] = *(const half8*)(lds + (wr * 64 + i * 32 + lo) * 128 + cs * 16);
                b[i] = *(const half8*)(lds + 16384 + (wc * 64 + i * 32 + lo) * 128 + cs * 16);
            }
            acc[0][0] = __builtin_amdgcn_mfma_f32_32x32x16_f16(a[0], b[0], acc[0][0], 0, 0, 0);
            acc[0][1] = __builtin_amdgcn_mfma_f32_32x32x16_f16(a[0], b[1], acc[0][1], 0, 0, 0);
            acc[1][0] = __builtin_amdgcn_mfma_f32_32x32x16_f16(a[1], b[0], acc[1][0], 0, 0, 0);
            acc[1][1] = __builtin_amdgcn_mfma_f32_32x32x16_f16(a[1], b[1], acc[1][1], 0, 0, 0);
        }
        __syncthreads();
    }

    if (z < 2) {
        _Float16* C = z == 0 ? qhf : khf;
#pragma unroll
        for (int j = 0; j < 2; ++j) {
            int n = bn + wc * 64 + j * 32 + lo;
            int h = n >> 6, d = n & 63;
#pragma unroll
            for (int i = 0; i < 2; ++i) {
                int mb2 = bm + wr * 64 + i * 32 + 4 * hi;
#pragma unroll
                for (int r = 0; r < 16; ++r) {
                    int m = mb2 + (r & 3) + 8 * (r >> 2);
                    int b = m >> 11, t = m & (TT - 1);
                    C[((size_t)(b * HH + h) * TT + t) * 64 + d] = (_Float16)acc[i][j][r];
                }
            }
        }
    } else {
#pragma unroll
        for (int j = 0; j < 2; ++j) {
            int n = bn + wc * 64 + j * 32 + lo;
            int h = n >> 6, d = n & 63;
#pragma unroll
            for (int i = 0; i < 2; ++i) {
                int mb2 = bm + wr * 64 + i * 32 + 4 * hi;
                int b = mb2 >> 11, tb = mb2 & (TT - 1);
#pragma unroll
                for (int r4 = 0; r4 < 4; ++r4) {
                    half4 hv = {(_Float16)acc[i][j][4 * r4 + 0], (_Float16)acc[i][j][4 * r4 + 1],
                                (_Float16)acc[i][j][4 * r4 + 2], (_Float16)acc[i][j][4 * r4 + 3]};
                    *(half4*)(vtf + ((size_t)(b * HH + h) * 64 + d) * TT + tb + 8 * r4) = hv;
                }
            }
        }
    }
}

// ---------------- MFMA flash attention (fp16, swapped S^T / O^T) -------------
__global__ __launch_bounds__(256) void attn_mfma(
    const _Float16* __restrict__ qh, const _Float16* __restrict__ kh,
    const _Float16* __restrict__ vt, const unsigned* __restrict__ maskbits,
    const float* __restrict__ btable, _Float16* __restrict__ Oout)
{
    int bid = blockIdx.x;
    int xcd = bid & 7, j = bid >> 3;
    int qt = j & 15, bh = xcd + 8 * (j >> 4);
    int h = bh & 15, b = bh >> 4;
    int tid = threadIdx.x;
    int wv = tid >> 6, lane = tid & 63, lo = lane & 31, hi = lane >> 5;
    int q0 = qt * 128 + wv * 32;

    const size_t bhoff = (size_t)(b * HH + h);
    const _Float16* Q = qh + (bhoff * TT + q0) * 64;
    const _Float16* K = kh + bhoff * TT * 64;
    const _Float16* V = vt + bhoff * 64 * TT;

    half8 qf[4];
#pragma unroll
    for (int c = 0; c < 4; ++c)
        qf[c] = *(const half8*)(Q + (size_t)lo * 64 + c * 16 + hi * 8);

    const float* bt = btable + h * NREL + (TT - 1) - (q0 + lo) + 4 * hi;
    const unsigned* mw = maskbits + ((size_t)b * TT + q0 + lo) * 64;

    f32x16 acco0 = zero16(), acco1 = zero16();
    float m = -INFINITY, l = 0.f;

    for (int kt = 0; kt < TT / 64; ++kt) {
        int k0 = kt * 64;
        half8 kf[2][4];
#pragma unroll
        for (int g = 0; g < 2; ++g)
#pragma unroll
            for (int c = 0; c < 4; ++c)
                kf[g][c] = *(const half8*)(K + (size_t)(k0 + 32 * g + lo) * 64 + c * 16 + hi * 8);
        unsigned wm0 = mw[2 * kt], wm1 = mw[2 * kt + 1];

        f32x16 accs0 = zero16(), accs1 = zero16();
        __builtin_amdgcn_s_setprio(1);
#pragma unroll
        for (int c = 0; c < 4; ++c) {
            accs0 = __builtin_amdgcn_mfma_f32_32x32x16_f16(kf[0][c], qf[c], accs0, 0, 0, 0);
            accs1 = __builtin_amdgcn_mfma_f32_32x32x16_f16(kf[1][c], qf[c], accs1, 0, 0, 0);
        }
        __builtin_amdgcn_s_setprio(0);

        float p[2][16];
        unsigned ws0 = wm0 >> (hi * 4), ws1 = wm1 >> (hi * 4);
#pragma unroll
        for (int r = 0; r < 16; ++r) {
            int sh = (r & 3) + 8 * (r >> 2);
            float s0 = fmaf(accs0[r], 0.125f, bt[k0 + sh]);
            float s1 = fmaf(accs1[r], 0.125f, bt[k0 + sh + 32]);
            p[0][r] = ((ws0 >> sh) & 1) ? s0 : -1e9f;
            p[1][r] = ((ws1 >> sh) & 1) ? s1 : -1e9f;
        }

        float tm = p[0][0];
#pragma unroll
        for (int g = 0; g < 2; ++g)
#pragma unroll
            for (int r = 0; r < 16; ++r) tm = fmaxf(tm, p[g][r]);
        tm = fmaxf(tm, __shfl_xor(tm, 32));
        float mnew = fmaxf(m, tm);
        float corr = __expf(m - mnew);
        float rs = 0.f;
#pragma unroll
        for (int g = 0; g < 2; ++g)
#pragma unroll
            for (int r = 0; r < 16; ++r) {
                p[g][r] = __expf(p[g][r] - mnew);
                rs += p[g][r];
            }
        rs += __shfl_xor(rs, 32);
        l = l * corr + rs; m = mnew;
#pragma unroll
        for (int r = 0; r < 16; ++r) { acco0[r] *= corr; acco1[r] *= corr; }

        half8 vf[2][4];
#pragma unroll
        for (int dg = 0; dg < 2; ++dg)
#pragma unroll
            for (int c = 0; c < 4; ++c)
                vf[dg][c] = *(const half8*)(V + (size_t)(32 * dg + lo) * TT + k0 + c * 16 + hi * 8);

        half8 pb[4];
#pragma unroll
        for (int g = 0; g < 2; ++g)
#pragma unroll
            for (int hc = 0; hc < 2; ++hc) {
                int r0 = hc * 8;
                unsigned w0 = pkh(p[g][r0 + 0], p[g][r0 + 1]);
                unsigned w2 = pkh(p[g][r0 + 4], p[g][r0 + 5]);
                asm("v_permlane32_swap_b32 %0, %1" : "+v"(w0), "+v"(w2));
                unsigned w1 = pkh(p[g][r0 + 2], p[g][r0 + 3]);
                unsigned w3 = pkh(p[g][r0 + 6], p[g][r0 + 7]);
                asm("v_permlane32_swap_b32 %0, %1" : "+v"(w1), "+v"(w3));
                union { int4v i; half8 hf; } cv;
                cv.i = (int4v){(int)w0, (int)w1, (int)w2, (int)w3};
                pb[2 * g + hc] = cv.hf;
            }

        __builtin_amdgcn_s_setprio(1);
#pragma unroll
        for (int c = 0; c < 4; ++c) {
            acco0 = __builtin_amdgcn_mfma_f32_32x32x16_f16(vf[0][c], pb[c], acco0, 0, 0, 0);
            acco1 = __builtin_amdgcn_mfma_f32_32x32x16_f16(vf[1][c], pb[c], acco1, 0, 0, 0);
        }
        __builtin_amdgcn_s_setprio(0);
    }

    float inv = 1.f / l;
    _Float16* op = Oout + (bhoff * TT + q0 + lo) * 64;
#pragma unroll
    for (int r4 = 0; r4 < 4; ++r4) {
        int d0 = 8 * r4 + 4 * hi;
        half4 h0 = {(_Float16)(acco0[4 * r4 + 0] * inv), (_Float16)(acco0[4 * r4 + 1] * inv),
                    (_Float16)(acco0[4 * r4 + 2] * inv), (_Float16)(acco0[4 * r4 + 3] * inv)};
        *(half4*)(op + d0) = h0;
        half4 h1 = {(_Float16)(acco1[4 * r4 + 0] * inv), (_Float16)(acco1[4 * r4 + 1] * inv),
                    (_Float16)(acco1[4 * r4 + 2] * inv), (_Float16)(acco1[4 * r4 + 3] * inv)};
        *(half4*)(op + d0 + 32) = h1;
    }
}

// ---------------- fc GEMM + fused bias_write ---------------------------------
// blocks [0,256): fc out0 = O @ WTfc; blocks [256,2304): expand out1 bias.
__global__ __launch_bounds__(256) void fc_bias_kernel(
    const _Float16* __restrict__ O, const _Float16* __restrict__ Bt,
    float* __restrict__ out0, const float* __restrict__ btable,
    float* __restrict__ out1)
{
    __shared__ __align__(16) char lds[32768];
    int bid = blockIdx.x, tid = threadIdx.x;
    if (bid >= 256) {                      // ---- bias expansion ----
        const int n4 = HH * TT * TT / 4, stride = 2048 * 256;
        for (int i4 = (bid - 256) * 256 + tid; i4 < n4; i4 += stride) {
            int i = i4 * 4;
            int kk = i & (TT - 1);
            int qq = (i >> 11) & (TT - 1);
            int hh2 = i >> 22;
            const float* btp = btable + hh2 * NREL + (kk - qq + (TT - 1));
            float4 vv = make_float4(btp[0], btp[1], btp[2], btp[3]);
            reinterpret_cast<float4*>(out1)[i4] = vv;
        }
        return;
    }
    // ---- fc GEMM, 128x128 tile, gload_lds ----
    int bm = (bid & 31) * 128, bn = (bid >> 5) * 128;
    int wv = tid >> 6, lane = tid & 63, lo = lane & 31, hi = lane >> 5;
    int wr = wv >> 1, wc = wv & 1;
    int srow = wv * 32 + (lane >> 3);
    int scol = (lane & 7) * 8;
    int bb = bm >> 11, tbase = bm & (TT - 1);

    f32x16 acc[2][2];
    acc[0][0] = zero16(); acc[0][1] = zero16();
    acc[1][0] = zero16(); acc[1][1] = zero16();

    for (int kt = 0; kt < 16; ++kt) {
        const _Float16* Ab = O + ((size_t)(bb * HH + kt) * TT + tbase) * 64;
#pragma unroll
        for (int t = 0; t < 4; ++t) {
            gload16(Ab + (size_t)(srow + t * 8) * 64 + scol,
                    lds + wv * 4096 + t * 1024);
            gload16(Bt + (size_t)(bn + srow + t * 8) * DMODEL + kt * 64 + scol,
                    lds + 16384 + wv * 4096 + t * 1024);
        }
        __syncthreads();
#pragma unroll
        for (int kk = 0; kk < 4; ++kk) {
            int cs = 2 * kk + hi;
            half8 a[2], b[2];
#pragma unroll
            for (int i = 0; i < 2; ++i) {
                a[i] = *(const half8*)(lds + (wr * 64 + i * 32 + lo) * 128 + cs * 16);
                b[i] = *(const half8*)(lds + 16384 + (wc * 64 + i * 32 + lo) * 128 + cs * 16);
            }
            acc[0][0] = __builtin_amdgcn_mfma_f32_32x32x16_f16(a[0], b[0], acc[0][0], 0, 0, 0);
            acc[0][1] = __builtin_amdgcn_mfma_f32_32x32x16_f16(a[0], b[1], acc[0][1], 0, 0, 0);
            acc[1][0] = __builtin_amdgcn_mfma_f32_32x32x16_f16(a[1], b[0], acc[1][0], 0, 0, 0);
            acc[1][1] = __builtin_amdgcn_mfma_f32_32x32x16_f16(a[1], b[1], acc[1][1], 0, 0, 0);
        }
        __syncthreads();
    }

#pragma unroll
    for (int j = 0; j < 2; ++j) {
        int n = bn + wc * 64 + j * 32 + lo;
#pragma unroll
        for (int i = 0; i < 2; ++i) {
            int mb2 = bm + wr * 64 + i * 32 + 4 * hi;
#pragma unroll
            for (int r = 0; r < 16; ++r) {
                int m = mb2 + (r & 3) + 8 * (r >> 2);
                out0[(size_t)m * DMODEL + n] = acc[i][j][r];
            }
        }
    }
}

// ---------------------------------------------------------------------------
extern "C" void kernel_launch(void* const* d_in, const int* in_sizes, int n_in,
                              void* d_out, int out_size, void* d_ws, size_t ws_size,
                              hipStream_t stream) {
    const float* q        = (const float*)d_in[0];
    const float* k        = (const float*)d_in[1];
    const float* v        = (const float*)d_in[2];
    const int*   mask     = (const int*)  d_in[3];
    const float* Wq       = (const float*)d_in[4];
    const float* Wk       = (const float*)d_in[5];
    const float* Wv       = (const float*)d_in[6];
    const float* Wfc      = (const float*)d_in[7];
    const float* rel_bias = (const float*)d_in[8];

    float* out0 = (float*)d_out;                       // [B][T][1024]
    float* out1 = out0 + (size_t)BB * TT * DMODEL;     // [H][T][T]

    char* w = (char*)d_ws;
    _Float16* q16 = (_Float16*)(w);                    // [0,8MB)   later: O
    _Float16* k16 = (_Float16*)(w + ((size_t)8  << 20));
    _Float16* v16 = (_Float16*)(w + ((size_t)16 << 20));
    _Float16* qhf = (_Float16*)(w + ((size_t)24 << 20));
    _Float16* khf = (_Float16*)(w + ((size_t)32 << 20));
    _Float16* WT  = (_Float16*)(w + ((size_t)40 << 20)); // 4 x 2MB
    float*    btable = (float*)(w + ((size_t)48 << 20));
    unsigned* mbits  = (unsigned*)(w + ((size_t)48 << 20) + ((size_t)1 << 19));
    bool big = ws_size >= ((size_t)58 << 20);
    _Float16* vtf = big ? (_Float16*)(w + ((size_t)49 << 20) + ((size_t)1 << 19))
                        : k16;                          // fallback: alias k16
    _Float16* O = q16;

    prep_kernel<<<dim3(40192), dim3(256), 0, stream>>>(
        q, k, v, mask, Wq, Wk, Wv, Wfc, rel_bias, q16, k16, v16, WT, btable, mbits);

    if (big) {
        gemm_proj3<<<dim3(32, 8, 3), dim3(256), 0, stream>>>(q16, k16, v16, WT,
                                                             qhf, khf, vtf, 0);
    } else {
        gemm_proj3<<<dim3(32, 8, 1), dim3(256), 0, stream>>>(q16, k16, v16, WT, qhf, khf, vtf, 0);
        gemm_proj3<<<dim3(32, 8, 1), dim3(256), 0, stream>>>(q16, k16, v16, WT, qhf, khf, vtf, 1);
        gemm_proj3<<<dim3(32, 8, 1), dim3(256), 0, stream>>>(q16, k16, v16, WT, qhf, khf, vtf, 2);
    }

    attn_mfma<<<dim3(BB * HH * 16), dim3(256), 0, stream>>>(
        qhf, khf, vtf, mbits, btable, O);

    fc_bias_kernel<<<dim3(2304), dim3(256), 0, stream>>>(
        O, WT + (size_t)3 * DMODEL * DMODEL, out0, btable, out1);
}

// Round 5
// 284.884 us; speedup vs baseline: 4.9972x; 1.0223x over previous
//
#include <hip/hip_runtime.h>
#include <math.h>

#define TT 2048
#define BB 2
#define HH 16
#define DMODEL 1024
#define NREL 4095                      // 2*TT-1

typedef __attribute__((ext_vector_type(8)))  _Float16 half8;
typedef __attribute__((ext_vector_type(4)))  _Float16 half4;
typedef __attribute__((ext_vector_type(16))) float    f32x16;
typedef __attribute__((ext_vector_type(4)))  int      int4v;

__device__ __forceinline__ f32x16 zero16() {
    f32x16 v;
#pragma unroll
    for (int i = 0; i < 16; ++i) v[i] = 0.f;
    return v;
}

__device__ __forceinline__ unsigned pkh(float a, float b) {
    union { _Float16 h[2]; unsigned u; } x;
    x.h[0] = (_Float16)a; x.h[1] = (_Float16)b;
    return x.u;
}

// async global->LDS, 16B per lane; LDS dest = wave-uniform base + lane*16
__device__ __forceinline__ void gload16(const void* g, void* l) {
    __builtin_amdgcn_global_load_lds(
        (const __attribute__((address_space(1))) void*)g,
        (__attribute__((address_space(3))) void*)l, 16, 0, 0);
}

// ---------------- bucket (exact-integer replication of reference log math) ---
__device__ __forceinline__ int rel_bucket(int rel) {
    int base = rel > 0 ? 16 : 0;
    int r = rel < 0 ? -rel : rel;
    int lb;
    if (r < 8)       lb = r;
    else if (r < 12) lb = 8;
    else if (r < 16) lb = 9;
    else if (r < 23) lb = 10;
    else if (r < 32) lb = 11;
    else if (r < 46) lb = 12;
    else if (r < 64) lb = 13;
    else if (r < 91) lb = 14;
    else             lb = 15;
    return base + lb;
}

// ---------------- fused prep: bias_table | wtrans | cvt16 x3 | maskpack ------
// blocks: [0,256) bias_table; [256,1280) wtrans; [1280,7424) cvt; [7424,40192) maskpack
__global__ __launch_bounds__(256) void prep_kernel(
    const float* __restrict__ q, const float* __restrict__ k,
    const float* __restrict__ v, const int* __restrict__ mask,
    const float* __restrict__ W0, const float* __restrict__ W1,
    const float* __restrict__ W2, const float* __restrict__ W3,
    const float* __restrict__ rel_bias,
    _Float16* __restrict__ q16, _Float16* __restrict__ k16,
    _Float16* __restrict__ v16, _Float16* __restrict__ WT,
    float* __restrict__ btable, unsigned* __restrict__ mb)
{
    __shared__ float t[64][65];
    int bid = blockIdx.x, tid = threadIdx.x;
    if (bid < 256) {
        int idx = bid * 256 + tid;
        if (idx < HH * NREL) {
            int h = idx / NREL, ri = idx % NREL;
            btable[idx] = rel_bias[rel_bucket(ri - (TT - 1)) * HH + h];
        }
    } else if (bid < 1280) {
        int zz = (bid - 256) >> 8, inner = (bid - 256) & 255;
        const float* src = zz == 0 ? W0 : zz == 1 ? W1 : zz == 2 ? W2 : W3;
        _Float16* dst = WT + (size_t)zz * DMODEL * DMODEL;
        int k0 = (inner >> 4) * 64, n0 = (inner & 15) * 64;
        int r = tid >> 4, c4 = (tid & 15) * 4;
#pragma unroll
        for (int i = 0; i < 4; ++i) {
            float4 vv = *(const float4*)(src + (size_t)(k0 + r + 16 * i) * DMODEL + n0 + c4);
            t[r + 16 * i][c4] = vv.x; t[r + 16 * i][c4 + 1] = vv.y;
            t[r + 16 * i][c4 + 2] = vv.z; t[r + 16 * i][c4 + 3] = vv.w;
        }
        __syncthreads();
        int rn = tid >> 2, ck = (tid & 3) * 16;
        half8 h0, h1;
#pragma unroll
        for (int j = 0; j < 8; ++j) h0[j] = (_Float16)t[ck + j][rn];
#pragma unroll
        for (int j = 0; j < 8; ++j) h1[j] = (_Float16)t[ck + 8 + j][rn];
        *(half8*)(dst + (size_t)(n0 + rn) * DMODEL + k0 + ck) = h0;
        *(half8*)(dst + (size_t)(n0 + rn) * DMODEL + k0 + ck + 8) = h1;
    } else if (bid < 7424) {
        int zz = (bid - 1280) >> 11, inner = (bid - 1280) & 2047;
        const float* src = zz == 0 ? q : zz == 1 ? k : v;
        _Float16* dst = zz == 0 ? q16 : zz == 1 ? k16 : v16;
        int i = inner * 256 + tid;
        const float4* in4 = (const float4*)src;
        float4 v0 = in4[(size_t)i * 2], v1 = in4[(size_t)i * 2 + 1];
        half8 h = {(_Float16)v0.x, (_Float16)v0.y, (_Float16)v0.z, (_Float16)v0.w,
                   (_Float16)v1.x, (_Float16)v1.y, (_Float16)v1.z, (_Float16)v1.w};
        *(half8*)(dst + (size_t)i * 8) = h;
    } else {
        int g = (bid - 7424) * 256 + tid;
        int vv = mask[g];
        unsigned long long bal = __ballot(vv != 0);
        if ((g & 63) == 0) {
            int word = g >> 5;
            mb[word]     = (unsigned)bal;
            mb[word + 1] = (unsigned)(bal >> 32);
        }
    }
}

// ---------------- fused projection MFMA GEMM (z: 0=q,1=k,2=v) ----------------
// A f16 row-major [4096][1024]; Bt = WT[n][k]; 128x128 tile, BK=64,
// double-buffered gload_lds (2-phase: stage next || compute cur, 1 barrier/step)
__global__ __launch_bounds__(256) void gemm_proj3(
    const _Float16* __restrict__ q16, const _Float16* __restrict__ k16,
    const _Float16* __restrict__ v16, const _Float16* __restrict__ WT,
    _Float16* __restrict__ qhf, _Float16* __restrict__ khf,
    _Float16* __restrict__ vtf, int zbase)
{
    __shared__ __align__(16) char lds[65536];   // 2 x {A [0,16K), B [16K,32K)}
    int z = zbase + blockIdx.z;
    const _Float16* A  = z == 0 ? q16 : z == 1 ? k16 : v16;
    const _Float16* Bt = WT + (size_t)z * DMODEL * DMODEL;
    int bm = blockIdx.x * 128, bn = blockIdx.y * 128;
    int tid = threadIdx.x;
    int wv = tid >> 6, lane = tid & 63, lo = lane & 31, hi = lane >> 5;
    int wr = wv >> 1, wc = wv & 1;
    int srow = wv * 32 + (lane >> 3);
    int scol = (lane & 7) * 8;
    const _Float16* Abase = A  + (size_t)(bm + srow) * DMODEL + scol;
    const _Float16* Bbase = Bt + (size_t)(bn + srow) * DMODEL + scol;

    f32x16 acc[2][2];
    acc[0][0] = zero16(); acc[0][1] = zero16();
    acc[1][0] = zero16(); acc[1][1] = zero16();

    auto stage = [&](int buf, int kt) {
#pragma unroll
        for (int t = 0; t < 4; ++t) {
            gload16(Abase + (size_t)t * 8 * DMODEL + kt * 64, lds + buf + wv * 4096 + t * 1024);
            gload16(Bbase + (size_t)t * 8 * DMODEL + kt * 64, lds + buf + 16384 + wv * 4096 + t * 1024);
        }
    };
    auto compute = [&](int buf) {
#pragma unroll
        for (int kk = 0; kk < 4; ++kk) {
            int cs = 2 * kk + hi;
            half8 a[2], b[2];
#pragma unroll
            for (int i = 0; i < 2; ++i) {
                a[i] = *(const half8*)(lds + buf + (wr * 64 + i * 32 + lo) * 128 + cs * 16);
                b[i] = *(const half8*)(lds + buf + 16384 + (wc * 64 + i * 32 + lo) * 128 + cs * 16);
            }
            acc[0][0] = __builtin_amdgcn_mfma_f32_32x32x16_f16(a[0], b[0], acc[0][0], 0, 0, 0);
            acc[0][1] = __builtin_amdgcn_mfma_f32_32x32x16_f16(a[0], b[1], acc[0][1], 0, 0, 0);
            acc[1][0] = __builtin_amdgcn_mfma_f32_32x32x16_f16(a[1], b[0], acc[1][0], 0, 0, 0);
            acc[1][1] = __builtin_amdgcn_mfma_f32_32x32x16_f16(a[1], b[1], acc[1][1], 0, 0, 0);
        }
    };

    stage(0, 0);
    __syncthreads();
    for (int kt = 0; kt < 16; kt += 2) {
        stage(32768, kt + 1);              // prefetch odd tile
        compute(0);                         // compute even tile
        __syncthreads();
        stage(0, kt + 2 < 16 ? kt + 2 : 15); // prefetch next even tile
        compute(32768);                     // compute odd tile
        __syncthreads();
    }

    if (z < 2) {
        _Float16* C = z == 0 ? qhf : khf;
#pragma unroll
        for (int j = 0; j < 2; ++j) {
            int n = bn + wc * 64 + j * 32 + lo;
            int h = n >> 6, d = n & 63;
#pragma unroll
            for (int i = 0; i < 2; ++i) {
                int mb2 = bm + wr * 64 + i * 32 + 4 * hi;
#pragma unroll
                for (int r = 0; r < 16; ++r) {
                    int m = mb2 + (r & 3) + 8 * (r >> 2);
                    int b = m >> 11, t = m & (TT - 1);
                    C[((size_t)(b * HH + h) * TT + t) * 64 + d] = (_Float16)acc[i][j][r];
                }
            }
        }
    } else {
#pragma unroll
        for (int j = 0; j < 2; ++j) {
            int n = bn + wc * 64 + j * 32 + lo;
            int h = n >> 6, d = n & 63;
#pragma unroll
            for (int i = 0; i < 2; ++i) {
                int mb2 = bm + wr * 64 + i * 32 + 4 * hi;
                int b = mb2 >> 11, tb = mb2 & (TT - 1);
#pragma unroll
                for (int r4 = 0; r4 < 4; ++r4) {
                    half4 hv = {(_Float16)acc[i][j][4 * r4 + 0], (_Float16)acc[i][j][4 * r4 + 1],
                                (_Float16)acc[i][j][4 * r4 + 2], (_Float16)acc[i][j][4 * r4 + 3]};
                    *(half4*)(vtf + ((size_t)(b * HH + h) * 64 + d) * TT + tb + 8 * r4) = hv;
                }
            }
        }
    }
}

// ---------------- MFMA flash attention (fp16, swapped S^T / O^T) -------------
// Banded bias: outside |k-q|<91 the bias is a per-head constant (bucket 15/31).
__global__ __launch_bounds__(256) void attn_mfma(
    const _Float16* __restrict__ qh, const _Float16* __restrict__ kh,
    const _Float16* __restrict__ vt, const unsigned* __restrict__ maskbits,
    const float* __restrict__ btable, _Float16* __restrict__ Oout)
{
    int bid = blockIdx.x;
    int xcd = bid & 7, j = bid >> 3;
    int qt = j & 15, bh = xcd + 8 * (j >> 4);
    int h = bh & 15, b = bh >> 4;
    int tid = threadIdx.x;
    int wv = tid >> 6, lane = tid & 63, lo = lane & 31, hi = lane >> 5;
    int q0 = qt * 128 + wv * 32;

    const size_t bhoff = (size_t)(b * HH + h);
    const _Float16* Q = qh + (bhoff * TT + q0) * 64;
    const _Float16* K = kh + bhoff * TT * 64;
    const _Float16* V = vt + bhoff * 64 * TT;

    half8 qf[4];
#pragma unroll
    for (int c = 0; c < 4; ++c)
        qf[c] = *(const half8*)(Q + (size_t)lo * 64 + c * 16 + hi * 8);

    const float* bt = btable + h * NREL + (TT - 1) - (q0 + lo) + 4 * hi;
    const float bias_l = btable[h * NREL];            // rel<=-91 (bucket 15)
    const float bias_r = btable[h * NREL + NREL - 1]; // rel>=+91 (bucket 31)
    const unsigned* mw = maskbits + ((size_t)b * TT + q0 + lo) * 64;

    f32x16 acco0 = zero16(), acco1 = zero16();
    float m = -INFINITY, l = 0.f;

    for (int kt = 0; kt < TT / 64; ++kt) {
        int k0 = kt * 64;
        half8 kf[2][4];
#pragma unroll
        for (int g = 0; g < 2; ++g)
#pragma unroll
            for (int c = 0; c < 4; ++c)
                kf[g][c] = *(const half8*)(K + (size_t)(k0 + 32 * g + lo) * 64 + c * 16 + hi * 8);
        unsigned wm0 = mw[2 * kt], wm1 = mw[2 * kt + 1];

        f32x16 accs0 = zero16(), accs1 = zero16();
        __builtin_amdgcn_s_setprio(1);
#pragma unroll
        for (int c = 0; c < 4; ++c) {
            accs0 = __builtin_amdgcn_mfma_f32_32x32x16_f16(kf[0][c], qf[c], accs0, 0, 0, 0);
            accs1 = __builtin_amdgcn_mfma_f32_32x32x16_f16(kf[1][c], qf[c], accs1, 0, 0, 0);
        }
        __builtin_amdgcn_s_setprio(0);

        // bias + mask (wave-uniform banded-bias branch), in place in accs
        unsigned ws0 = wm0 >> (hi * 4), ws1 = wm1 >> (hi * 4);
        bool rconst = k0 > q0 + 121;           // all keys: k - q >= 91
        bool lconst = k0 + 63 < q0 - 90;       // all keys: k - q <= -91
        if (rconst | lconst) {
            float bc = rconst ? bias_r : bias_l;
#pragma unroll
            for (int r = 0; r < 16; ++r) {
                int sh = (r & 3) + 8 * (r >> 2);
                float s0 = fmaf(accs0[r], 0.125f, bc);
                float s1 = fmaf(accs1[r], 0.125f, bc);
                accs0[r] = ((ws0 >> sh) & 1) ? s0 : -1e9f;
                accs1[r] = ((ws1 >> sh) & 1) ? s1 : -1e9f;
            }
        } else {
#pragma unroll
            for (int r = 0; r < 16; ++r) {
                int sh = (r & 3) + 8 * (r >> 2);
                float s0 = fmaf(accs0[r], 0.125f, bt[k0 + sh]);
                float s1 = fmaf(accs1[r], 0.125f, bt[k0 + sh + 32]);
                accs0[r] = ((ws0 >> sh) & 1) ? s0 : -1e9f;
                accs1[r] = ((ws1 >> sh) & 1) ? s1 : -1e9f;
            }
        }

        float tm = accs0[0];
#pragma unroll
        for (int r = 1; r < 16; ++r) tm = fmaxf(tm, accs0[r]);
#pragma unroll
        for (int r = 0; r < 16; ++r) tm = fmaxf(tm, accs1[r]);
        tm = fmaxf(tm, __shfl_xor(tm, 32));
        float mnew = fmaxf(m, tm);
        float corr = __expf(m - mnew);
        float rs = 0.f;
#pragma unroll
        for (int r = 0; r < 16; ++r) {
            accs0[r] = __expf(accs0[r] - mnew); rs += accs0[r];
        }
#pragma unroll
        for (int r = 0; r < 16; ++r) {
            accs1[r] = __expf(accs1[r] - mnew); rs += accs1[r];
        }
        rs += __shfl_xor(rs, 32);
        l = l * corr + rs; m = mnew;
#pragma unroll
        for (int r = 0; r < 16; ++r) { acco0[r] *= corr; acco1[r] *= corr; }

        half8 vf[2][4];
#pragma unroll
        for (int dg = 0; dg < 2; ++dg)
#pragma unroll
            for (int c = 0; c < 4; ++c)
                vf[dg][c] = *(const half8*)(V + (size_t)(32 * dg + lo) * TT + k0 + c * 16 + hi * 8);

        half8 pb[4];
#pragma unroll
        for (int g = 0; g < 2; ++g)
#pragma unroll
            for (int hc = 0; hc < 2; ++hc) {
                int r0 = hc * 8;
                float p0 = g ? accs1[r0 + 0] : accs0[r0 + 0];
                float p1 = g ? accs1[r0 + 1] : accs0[r0 + 1];
                float p2 = g ? accs1[r0 + 2] : accs0[r0 + 2];
                float p3 = g ? accs1[r0 + 3] : accs0[r0 + 3];
                float p4 = g ? accs1[r0 + 4] : accs0[r0 + 4];
                float p5 = g ? accs1[r0 + 5] : accs0[r0 + 5];
                float p6 = g ? accs1[r0 + 6] : accs0[r0 + 6];
                float p7 = g ? accs1[r0 + 7] : accs0[r0 + 7];
                unsigned w0 = pkh(p0, p1);
                unsigned w2 = pkh(p4, p5);
                asm("v_permlane32_swap_b32 %0, %1" : "+v"(w0), "+v"(w2));
                unsigned w1 = pkh(p2, p3);
                unsigned w3 = pkh(p6, p7);
                asm("v_permlane32_swap_b32 %0, %1" : "+v"(w1), "+v"(w3));
                union { int4v i; half8 hf; } cv;
                cv.i = (int4v){(int)w0, (int)w1, (int)w2, (int)w3};
                pb[2 * g + hc] = cv.hf;
            }

        __builtin_amdgcn_s_setprio(1);
#pragma unroll
        for (int c = 0; c < 4; ++c) {
            acco0 = __builtin_amdgcn_mfma_f32_32x32x16_f16(vf[0][c], pb[c], acco0, 0, 0, 0);
            acco1 = __builtin_amdgcn_mfma_f32_32x32x16_f16(vf[1][c], pb[c], acco1, 0, 0, 0);
        }
        __builtin_amdgcn_s_setprio(0);
    }

    float inv = 1.f / l;
    _Float16* op = Oout + (bhoff * TT + q0 + lo) * 64;
#pragma unroll
    for (int r4 = 0; r4 < 4; ++r4) {
        int d0 = 8 * r4 + 4 * hi;
        half4 h0 = {(_Float16)(acco0[4 * r4 + 0] * inv), (_Float16)(acco0[4 * r4 + 1] * inv),
                    (_Float16)(acco0[4 * r4 + 2] * inv), (_Float16)(acco0[4 * r4 + 3] * inv)};
        *(half4*)(op + d0) = h0;
        half4 h1 = {(_Float16)(acco1[4 * r4 + 0] * inv), (_Float16)(acco1[4 * r4 + 1] * inv),
                    (_Float16)(acco1[4 * r4 + 2] * inv), (_Float16)(acco1[4 * r4 + 3] * inv)};
        *(half4*)(op + d0 + 32) = h1;
    }
}

// ---------------- fc GEMM (dbuf 2-phase) + fused bias_write ------------------
// blocks [0,256): fc out0 = O @ WTfc; blocks [256,2304): expand out1 bias.
__global__ __launch_bounds__(256) void fc_bias_kernel(
    const _Float16* __restrict__ O, const _Float16* __restrict__ Bt,
    float* __restrict__ out0, const float* __restrict__ btable,
    float* __restrict__ out1)
{
    __shared__ __align__(16) char lds[65536];
    int bid = blockIdx.x, tid = threadIdx.x;
    if (bid >= 256) {                      // ---- bias expansion ----
        const int n4 = HH * TT * TT / 4, stride = 2048 * 256;
        for (int i4 = (bid - 256) * 256 + tid; i4 < n4; i4 += stride) {
            int i = i4 * 4;
            int kk = i & (TT - 1);
            int qq = (i >> 11) & (TT - 1);
            int hh2 = i >> 22;
            const float* btp = btable + hh2 * NREL + (kk - qq + (TT - 1));
            float4 vv = make_float4(btp[0], btp[1], btp[2], btp[3]);
            reinterpret_cast<float4*>(out1)[i4] = vv;
        }
        return;
    }
    // ---- fc GEMM, 128x128 tile, dbuf gload_lds ----
    int bm = (bid & 31) * 128, bn = (bid >> 5) * 128;
    int wv = tid >> 6, lane = tid & 63, lo = lane & 31, hi = lane >> 5;
    int wr = wv >> 1, wc = wv & 1;
    int srow = wv * 32 + (lane >> 3);
    int scol = (lane & 7) * 8;
    int bb = bm >> 11, tbase = bm & (TT - 1);
    const _Float16* Abase = O + ((size_t)(bb * HH) * TT + tbase + srow) * 64 + scol;
    const _Float16* Bbase = Bt + (size_t)(bn + srow) * DMODEL + scol;

    f32x16 acc[2][2];
    acc[0][0] = zero16(); acc[0][1] = zero16();
    acc[1][0] = zero16(); acc[1][1] = zero16();

    auto stage = [&](int buf, int kt) {
#pragma unroll
        for (int t = 0; t < 4; ++t) {
            gload16(Abase + (size_t)kt * TT * 64 + (size_t)t * 8 * 64, lds + buf + wv * 4096 + t * 1024);
            gload16(Bbase + (size_t)t * 8 * DMODEL + kt * 64, lds + buf + 16384 + wv * 4096 + t * 1024);
        }
    };
    auto compute = [&](int buf) {
#pragma unroll
        for (int kk = 0; kk < 4; ++kk) {
            int cs = 2 * kk + hi;
            half8 a[2], b[2];
#pragma unroll
            for (int i = 0; i < 2; ++i) {
                a[i] = *(const half8*)(lds + buf + (wr * 64 + i * 32 + lo) * 128 + cs * 16);
                b[i] = *(const half8*)(lds + buf + 16384 + (wc * 64 + i * 32 + lo) * 128 + cs * 16);
            }
            acc[0][0] = __builtin_amdgcn_mfma_f32_32x32x16_f16(a[0], b[0], acc[0][0], 0, 0, 0);
            acc[0][1] = __builtin_amdgcn_mfma_f32_32x32x16_f16(a[0], b[1], acc[0][1], 0, 0, 0);
            acc[1][0] = __builtin_amdgcn_mfma_f32_32x32x16_f16(a[1], b[0], acc[1][0], 0, 0, 0);
            acc[1][1] = __builtin_amdgcn_mfma_f32_32x32x16_f16(a[1], b[1], acc[1][1], 0, 0, 0);
        }
    };

    stage(0, 0);
    __syncthreads();
    for (int kt = 0; kt < 16; kt += 2) {
        stage(32768, kt + 1);
        compute(0);
        __syncthreads();
        stage(0, kt + 2 < 16 ? kt + 2 : 15);
        compute(32768);
        __syncthreads();
    }

#pragma unroll
    for (int j = 0; j < 2; ++j) {
        int n = bn + wc * 64 + j * 32 + lo;
#pragma unroll
        for (int i = 0; i < 2; ++i) {
            int mb2 = bm + wr * 64 + i * 32 + 4 * hi;
#pragma unroll
            for (int r = 0; r < 16; ++r) {
                int m = mb2 + (r & 3) + 8 * (r >> 2);
                out0[(size_t)m * DMODEL + n] = acc[i][j][r];
            }
        }
    }
}

// ---------------------------------------------------------------------------
extern "C" void kernel_launch(void* const* d_in, const int* in_sizes, int n_in,
                              void* d_out, int out_size, void* d_ws, size_t ws_size,
                              hipStream_t stream) {
    const float* q        = (const float*)d_in[0];
    const float* k        = (const float*)d_in[1];
    const float* v        = (const float*)d_in[2];
    const int*   mask     = (const int*)  d_in[3];
    const float* Wq       = (const float*)d_in[4];
    const float* Wk       = (const float*)d_in[5];
    const float* Wv       = (const float*)d_in[6];
    const float* Wfc      = (const float*)d_in[7];
    const float* rel_bias = (const float*)d_in[8];

    float* out0 = (float*)d_out;                       // [B][T][1024]
    float* out1 = out0 + (size_t)BB * TT * DMODEL;     // [H][T][T]

    char* w = (char*)d_ws;
    _Float16* q16 = (_Float16*)(w);                    // [0,8MB)   later: O
    _Float16* k16 = (_Float16*)(w + ((size_t)8  << 20));
    _Float16* v16 = (_Float16*)(w + ((size_t)16 << 20));
    _Float16* qhf = (_Float16*)(w + ((size_t)24 << 20));
    _Float16* khf = (_Float16*)(w + ((size_t)32 << 20));
    _Float16* WT  = (_Float16*)(w + ((size_t)40 << 20)); // 4 x 2MB
    float*    btable = (float*)(w + ((size_t)48 << 20));
    unsigned* mbits  = (unsigned*)(w + ((size_t)48 << 20) + ((size_t)1 << 19));
    bool big = ws_size >= ((size_t)58 << 20);
    _Float16* vtf = big ? (_Float16*)(w + ((size_t)49 << 20) + ((size_t)1 << 19))
                        : k16;                          // fallback: alias k16
    _Float16* O = q16;

    prep_kernel<<<dim3(40192), dim3(256), 0, stream>>>(
        q, k, v, mask, Wq, Wk, Wv, Wfc, rel_bias, q16, k16, v16, WT, btable, mbits);

    if (big) {
        gemm_proj3<<<dim3(32, 8, 3), dim3(256), 0, stream>>>(q16, k16, v16, WT,
                                                             qhf, khf, vtf, 0);
    } else {
        gemm_proj3<<<dim3(32, 8, 1), dim3(256), 0, stream>>>(q16, k16, v16, WT, qhf, khf, vtf, 0);
        gemm_proj3<<<dim3(32, 8, 1), dim3(256), 0, stream>>>(q16, k16, v16, WT, qhf, khf, vtf, 1);
        gemm_proj3<<<dim3(32, 8, 1), dim3(256), 0, stream>>>(q16, k16, v16, WT, qhf, khf, vtf, 2);
    }

    attn_mfma<<<dim3(BB * HH * 16), dim3(256), 0, stream>>>(
        qhf, khf, vtf, mbits, btable, O);

    fc_bias_kernel<<<dim3(2304), dim3(256), 0, stream>>>(
        O, WT + (size_t)3 * DMODEL * DMODEL, out0, btable, out1);
}